// Round 14
// baseline (865.358 us; speedup 1.0000x reference)
//
#include <hip/hip_runtime.h>

typedef __attribute__((ext_vector_type(8))) short s16x8;
typedef __attribute__((ext_vector_type(8))) _Float16 f16x8;
typedef __attribute__((ext_vector_type(4))) float f32x4;
typedef __attribute__((ext_vector_type(4))) unsigned short u16x4;
typedef unsigned short u16;

// ---------- bf16 helpers (RNE) ----------
__device__ __forceinline__ u16 f2bf(float x) {
  unsigned u = __builtin_bit_cast(unsigned, x);
  u = u + 0x7fffu + ((u >> 16) & 1u);
  return (u16)(u >> 16);
}
__device__ __forceinline__ float bf2f(u16 h) {
  return __builtin_bit_cast(float, (unsigned)h << 16);
}
__device__ __forceinline__ void split_bf(float x, u16 &h, u16 &l) {
  h = f2bf(x); l = f2bf(x - bf2f(h));
}
__device__ __forceinline__ u16 f2h(float x) {
  return __builtin_bit_cast(u16, (_Float16)x);
}

// ---------- async global -> LDS, 16B per lane ----------
typedef __attribute__((address_space(1))) const unsigned int as1c_u32;
typedef __attribute__((address_space(3))) unsigned int as3_u32;
__device__ __forceinline__ void gload16(const void* g, void* l) {
  __builtin_amdgcn_global_load_lds((as1c_u32*)g, (as3_u32*)l, 16, 0, 0);
}

// ---------- vectorized split: f32 -> hi/lo bf16 ----------
__global__ __launch_bounds__(256) void split_copy_k(
    const float* __restrict__ in, u16* __restrict__ oh, u16* __restrict__ ol, long n4) {
  const long i = (long)blockIdx.x * 256 + threadIdx.x;
  if (i >= n4) return;
  const f32x4 v = *(const f32x4*)(in + i * 4);
  u16x4 h, l;
#pragma unroll
  for (int e = 0; e < 4; ++e) { u16 hh, ll; split_bf(v[e], hh, ll); h[e] = hh; l[e] = ll; }
  *(u16x4*)(oh + i * 4) = h;
  *(u16x4*)(ol + i * 4) = l;
}

// ---------- f32 -> fp16 copy ----------
__global__ __launch_bounds__(256) void copy_f16_k(
    const float* __restrict__ in, u16* __restrict__ oh, long n4) {
  const long i = (long)blockIdx.x * 256 + threadIdx.x;
  if (i >= n4) return;
  const f32x4 v = *(const f32x4*)(in + i * 4);
  u16x4 h;
#pragma unroll
  for (int e = 0; e < 4; ++e) h[e] = f2h(v[e]);
  *(u16x4*)(oh + i * 4) = h;
}

// ---------- transpose from split bf16: mbS hi/lo [b][S=2048][D=1024] -> mbT [b][D][S] fp16 ----------
__global__ __launch_bounds__(256) void transpose2_k(
    const u16* __restrict__ inh, const u16* __restrict__ inl, u16* __restrict__ outT) {
  __shared__ u16 th[64][72], tl[64][72];
  const int b = blockIdx.z;
  const int s0 = blockIdx.x * 64, d0 = blockIdx.y * 64;
  const long base = (long)b * 2048 * 1024;
  const int t = threadIdx.x;
#pragma unroll
  for (int i = 0; i < 4; ++i) {
    const int idx = i * 256 + t;
    const int r = idx >> 4;          // s-row 0..63
    const int c4 = (idx & 15) * 4;   // d quad
    const long o = base + (long)(s0 + r) * 1024 + d0 + c4;
    *(u16x4*)&th[r][c4] = *(const u16x4*)&inh[o];
    *(u16x4*)&tl[r][c4] = *(const u16x4*)&inl[o];
  }
  __syncthreads();
  u16* pout = outT + (long)b * 1024 * 2048;
#pragma unroll
  for (int i = 0; i < 4; ++i) {
    const int idx = i * 256 + t;
    const int r = idx >> 4;          // d-row 0..63
    const int c4 = (idx & 15) * 4;   // s quad
    u16x4 v;
#pragma unroll
    for (int e = 0; e < 4; ++e)
      v[e] = f2h(bf2f(th[c4 + e][r]) + bf2f(tl[c4 + e][r]));
    *(u16x4*)&pout[(long)(d0 + r) * 2048 + s0 + c4] = v;
  }
}

// ---------- masked softmax over S=2048; P f32 -> out [T,B,S]; P fp16 packed in place ----------
__global__ __launch_bounds__(256) void softmax_k(
    float* __restrict__ alignBuf, const int* __restrict__ lens, float* __restrict__ outP) {
  const int row = blockIdx.x;          // b*1024 + t
  const int b = row >> 10;
  const int tt = row & 1023;
  const int len = lens[b];
  float* arow = alignBuf + (long)row * 2048;
  const int t = threadIdx.x;
  const int lane = t & 63, wv = t >> 6;
  float v[8];
  float mx = -3.0e38f;
#pragma unroll
  for (int j = 0; j < 8; ++j) {
    const int s = j * 256 + t;
    const float x = (s < len) ? arow[s] : -1.0e9f;   // skip masked loads
    v[j] = x;
    mx = fmaxf(mx, x);
  }
#pragma unroll
  for (int off = 32; off; off >>= 1) mx = fmaxf(mx, __shfl_xor(mx, off));
  __shared__ float redm[4], reds[4];
  if (lane == 0) redm[wv] = mx;
  __syncthreads();
  mx = fmaxf(fmaxf(redm[0], redm[1]), fmaxf(redm[2], redm[3]));
  float e[8]; float sum = 0.f;
#pragma unroll
  for (int j = 0; j < 8; ++j) { e[j] = __expf(v[j] - mx); sum += e[j]; }
#pragma unroll
  for (int off = 32; off; off >>= 1) sum += __shfl_xor(sum, off);
  if (lane == 0) reds[wv] = sum;
  __syncthreads();   // fences all reads of arow before in-place overwrite below
  sum = reds[0] + reds[1] + reds[2] + reds[3];
  const float inv = 1.0f / sum;
  u16* ph = (u16*)arow;          // [0,2048): P fp16 (first 4KB of the 8KB row)
  float* orow = outP + ((long)tt * 16 + b) * 2048;
#pragma unroll
  for (int j = 0; j < 8; ++j) {
    const int s = j * 256 + t;
    const float pv = e[j] * inv;
    orow[s] = pv;
    ph[s] = f2h(pv);             // exact 0 beyond len -> maskK in G3 exact
  }
}

// ========== Template B64: 128x128, BK=64, single-buf, glds, bf16 3-prod (G1/G2) ==========
// Round-7-proven gemm128w structure at NPROD=3 (NT=4, 64KB LDS, 2 barriers per 64-K).
// EP: 0 = f32 Cf; 1 = split bf16 Ch/Cl. MASK: 0 none; 1 = exit block if n0 >= lens[bz].
template<int EP, int MASK>
__global__ __launch_bounds__(256) void gemmB64(
    const u16* __restrict__ Ah, const u16* __restrict__ Al, int lda, long sA,
    const u16* __restrict__ Bh, const u16* __restrict__ Bl, int ldb, long sB,
    int K, const int* __restrict__ lens,
    float* __restrict__ Cf, u16* __restrict__ Ch, u16* __restrict__ Cl,
    int ldc, long sC, int lgx, int lgxy, int nwg) {
  __shared__ __align__(16) u16 lds[4][8192];   // 0=Ah 1=Bh 2=Al 3=Bl; [kc(8)][row(128)][8]

  const int orig = blockIdx.x;
  const int wg = (orig & 7) * (nwg >> 3) + (orig >> 3);
  const int bx = wg & ((1 << lgx) - 1);
  const int by = (wg >> lgx) & ((1 << (lgxy - lgx)) - 1);
  const int bz = wg >> lgxy;

  const long m0 = (long)by * 128;
  const long n0 = (long)bx * 128;

  if constexpr (MASK == 1) {
    if (n0 >= lens[bz]) return;        // block-uniform, before any barrier
  }

  const u16* pAh = Ah + (long)bz * sA;
  const u16* pAl = Al + (long)bz * sA;
  const u16* pBh = Bh + (long)bz * sB;
  const u16* pBl = Bl + (long)bz * sB;

  const int t = threadIdx.x;
  const int lane = t & 63;
  const int wv = t >> 6;
  const int wm = wv >> 1;
  const int wn = wv & 1;
  const int lk = lane >> 4;
  const int lr = lane & 15;

  f32x4 acc[4][4];
#pragma unroll
  for (int i = 0; i < 4; ++i)
#pragma unroll
    for (int j = 0; j < 4; ++j) acc[i][j] = 0.0f;

  for (int k0 = 0; k0 < K; k0 += 64) {
    __syncthreads();
#pragma unroll
    for (int j = 0; j < 4; ++j) {
      const int ci = (j * 4 + wv) * 64;   // wave-uniform entry base
      const int c = ci + lane;
      const int kc = c >> 7;              // 0..7, uniform within 64-entry chunk
      const int r = c & 127;
      const int k = k0 + kc * 8;
      const long aoff = (m0 + r) * (long)lda + k;
      gload16(pAh + aoff, &lds[0][ci * 8]);
      gload16(pAl + aoff, &lds[2][ci * 8]);
      const long boff = (n0 + r) * (long)ldb + k;
      gload16(pBh + boff, &lds[1][ci * 8]);
      gload16(pBl + boff, &lds[3][ci * 8]);
    }
    __syncthreads();

#pragma unroll
    for (int ks = 0; ks < 2; ++ks) {
      const int fb = (ks * 4 + lk) * 1024;
      s16x8 ah[4], al[4], bh[4], bl[4];
#pragma unroll
      for (int f = 0; f < 4; ++f) {
        const int ra = wm * 64 + f * 16 + lr;
        const int rb = wn * 64 + f * 16 + lr;
        ah[f] = *(const s16x8*)&lds[0][fb + ra * 8];
        bh[f] = *(const s16x8*)&lds[1][fb + rb * 8];
        al[f] = *(const s16x8*)&lds[2][fb + ra * 8];
        bl[f] = *(const s16x8*)&lds[3][fb + rb * 8];
      }
#pragma unroll
      for (int i = 0; i < 4; ++i)
#pragma unroll
        for (int j = 0; j < 4; ++j) {
          acc[i][j] = __builtin_amdgcn_mfma_f32_16x16x32_bf16(ah[i], bh[j], acc[i][j], 0, 0, 0);
          acc[i][j] = __builtin_amdgcn_mfma_f32_16x16x32_bf16(ah[i], bl[j], acc[i][j], 0, 0, 0);
          acc[i][j] = __builtin_amdgcn_mfma_f32_16x16x32_bf16(al[i], bh[j], acc[i][j], 0, 0, 0);
        }
    }
  }

#pragma unroll
  for (int fm = 0; fm < 4; ++fm)
#pragma unroll
    for (int fn = 0; fn < 4; ++fn)
#pragma unroll
      for (int r = 0; r < 4; ++r) {
        const long row = m0 + wm * 64 + fm * 16 + (lane >> 4) * 4 + r;
        const long col = n0 + wn * 64 + fn * 16 + lr;
        const float v = acc[fm][fn][r];
        if constexpr (EP == 0) {
          Cf[(long)bz * sC + row * ldc + col] = v;
        } else {
          u16 h, l; split_bf(v, h, l);
          const long o = (long)bz * sC + row * ldc + col;
          Ch[o] = h; Cl[o] = l;
        }
      }
}

// ========== Template W: 256x128 tile, BK=64, 512 thr (8 waves: 4m x 2n), fp16 1-prod ==========
// A 256xK fp16, optional switch to A2 at kSplitA (concat trick); B 128xK fp16.
// EP: 2 = tanh + [T,B,D] transposed f32 store; 3 = fp16 C store.
// MASK: 0 none; 2 = truncate K at ceil(lens[bz]/64)*64.
template<int EP, int MASK>
__global__ __launch_bounds__(512) void gemmW(
    const u16* __restrict__ A1, const u16* __restrict__ A2, int kSplitA, int lda, long sA,
    const u16* __restrict__ B, int ldb, long sB,
    int K, const int* __restrict__ lens,
    float* __restrict__ Cf, u16* __restrict__ Ch,
    int ldc, long sC, int lgx, int lgxy, int nwg) {
  __shared__ __align__(16) u16 ldsA[16384];  // [kc(8)][row(256)][8]  32KB
  __shared__ __align__(16) u16 ldsB[8192];   // [kc(8)][row(128)][8]  16KB

  const int orig = blockIdx.x;
  const int wg = (orig & 7) * (nwg >> 3) + (orig >> 3);
  const int bx = wg & ((1 << lgx) - 1);
  const int by = (wg >> lgx) & ((1 << (lgxy - lgx)) - 1);
  const int bz = wg >> lgxy;

  const long m0 = (long)by * 256;
  const long n0 = (long)bx * 128;

  int Klim = K;
  if constexpr (MASK == 2) {
    const int kl = (lens[bz] + 63) & ~63;
    Klim = kl < K ? kl : K;
  }

  const u16* pA1 = A1 + (long)bz * sA;
  const u16* pA2 = A2 + (long)bz * sA;
  const u16* pB  = B  + (long)bz * sB;

  const int t = threadIdx.x;
  const int lane = t & 63;
  const int wv = t >> 6;        // 0..7
  const int wm = wv >> 1;       // 0..3  (M quarter, 64 rows)
  const int wn = wv & 1;        // 0..1  (N half, 64 cols)
  const int lk = lane >> 4;     // 0..3
  const int lr = lane & 15;

  f32x4 acc[4][4];
#pragma unroll
  for (int i = 0; i < 4; ++i)
#pragma unroll
    for (int j = 0; j < 4; ++j) acc[i][j] = 0.0f;

  for (int k0 = 0; k0 < Klim; k0 += 64) {
    __syncthreads();
    // stage A 256x64 (2048 entries of 8 halves), 4 chunks/lane
#pragma unroll
    for (int j = 0; j < 4; ++j) {
      const int ci = (j * 8 + wv) * 64;   // 64-aligned -> kc uniform in chunk
      const int c = ci + lane;
      const int kc = c >> 8;              // 0..7
      const int r = c & 255;
      const int k = k0 + kc * 8;
      const u16* a = pA1; long ka = k;
      if (k >= kSplitA) { a = pA2; ka = k - kSplitA; }
      gload16(a + (m0 + r) * (long)lda + ka, &ldsA[ci * 8]);
    }
    // stage B 128x64 (1024 entries), 2 chunks/lane
#pragma unroll
    for (int j = 0; j < 2; ++j) {
      const int ci = (j * 8 + wv) * 64;
      const int c = ci + lane;
      const int kc = c >> 7;              // 0..7
      const int r = c & 127;
      const int k = k0 + kc * 8;
      gload16(pB + (n0 + r) * (long)ldb + k, &ldsB[ci * 8]);
    }
    __syncthreads();

#pragma unroll
    for (int ks = 0; ks < 2; ++ks) {
      const int kc = ks * 4 + lk;         // 0..7
      f16x8 a[4], b[4];
#pragma unroll
      for (int f = 0; f < 4; ++f) {
        const int ra = wm * 64 + f * 16 + lr;
        const int rb = wn * 64 + f * 16 + lr;
        a[f] = *(const f16x8*)&ldsA[(kc * 256 + ra) * 8];
        b[f] = *(const f16x8*)&ldsB[(kc * 128 + rb) * 8];
      }
#pragma unroll
      for (int i = 0; i < 4; ++i)
#pragma unroll
        for (int j = 0; j < 4; ++j)
          acc[i][j] = __builtin_amdgcn_mfma_f32_16x16x32_f16(a[i], b[j], acc[i][j], 0, 0, 0);
    }
  }

#pragma unroll
  for (int fm = 0; fm < 4; ++fm)
#pragma unroll
    for (int fn = 0; fn < 4; ++fn)
#pragma unroll
      for (int r = 0; r < 4; ++r) {
        const long row = m0 + wm * 64 + fm * 16 + (lane >> 4) * 4 + r;
        const long col = n0 + wn * 64 + fn * 16 + lr;
        const float v = acc[fm][fn][r];
        if constexpr (EP == 2) {
          const long bb = row >> 10;       // batch (T=1024)
          const long tt = row & 1023;      // t
          Cf[(tt * 16 + bb) * (long)ldc + col] = tanhf(v);
        } else {
          Ch[(long)bz * sC + row * ldc + col] = f2h(v);
        }
      }
}

extern "C" void kernel_launch(void* const* d_in, const int* in_sizes, int n_in,
                              void* d_out, int out_size, void* d_ws, size_t ws_size,
                              hipStream_t stream) {
  (void)in_sizes; (void)n_in; (void)out_size; (void)ws_size;
  const float* src = (const float*)d_in[0];   // [16,1024,1024]
  const float* mb  = (const float*)d_in[1];   // [16,2048,1024]
  const int*   lens= (const int*)d_in[2];     // [16]
  const float* Wi  = (const float*)d_in[3];   // [1024,1024]
  const float* Wo  = (const float*)d_in[4];   // [1024,2048]
  float* out = (float*)d_out;                 // attn [T,B,D] f32, then P [T,B,S] f32

  // workspace (384 MiB) — round-12 proven layout
  char* p = (char*)d_ws;
  u16* mbS_hi  = (u16*)p;                         // 64 MiB (read by G2+transpose2, then -> srcF16/Wo_f16)
  u16* mbS_lo  = (u16*)(p + (64L << 20));         // 64 MiB (read by G2+transpose2, then dead)
  u16* srcU_hi = (u16*)(p + (128L << 20));        // 32 MiB bf16 (G1; dead after -> mbT)
  u16* srcU_lo = (u16*)(p + (160L << 20));        // 32 MiB bf16 (G1; dead after -> mbT)
  u16* htc_hi  = (u16*)(p + (192L << 20));        // 32 MiB h_t hi -> c fp16 (G3 out)
  u16* htc_lo  = (u16*)(p + (224L << 20));        // 32 MiB h_t lo (dead after G2)
  float* alignBuf = (float*)(p + (256L << 20));   // 128 MiB [16][1024][2048] f32
  u16* Wi_hi = (u16*)alignBuf;                    // borrow head of alignBuf pre-G2
  u16* Wi_lo = Wi_hi + 1048576;
  u16* mbT    = srcU_hi;                          // [b][D][S] fp16, 64 MiB = srcU region exactly
  u16* srcF16 = mbS_hi;                           // 32 MiB (16384x1024 fp16), after transpose2 read
  u16* Wo_f16 = mbS_hi + 16777216;                // 4 MiB at +32 MiB

  dim3 blk(256);
  split_copy_k<<<dim3(32768), blk, 0, stream>>>(mb,  mbS_hi, mbS_lo, 8388608L);
  split_copy_k<<<dim3(16384), blk, 0, stream>>>(src, srcU_hi, srcU_lo, 4194304L);
  split_copy_k<<<dim3(1024),  blk, 0, stream>>>(Wi,  Wi_hi,  Wi_lo,  262144L);

  // G1: h_t = src @ Wi^T  (M=16384,N=1024,K=1024), bf16 3-prod, BK=64, split store
  gemmB64<1, 0><<<dim3(1024), blk, 0, stream>>>(
      srcU_hi, srcU_lo, 1024, 0L,
      Wi_hi, Wi_lo, 1024, 0L,
      1024, lens,
      nullptr, htc_hi, htc_lo, 1024, 0L,
      3, 10, 1024);

  // G2: align[b] = h_t[b] @ mb[b]^T  (M=1024,N=2048,K=1024)x16, bf16 3-prod, BK=64, f32 store, maskN
  gemmB64<0, 1><<<dim3(2048), blk, 0, stream>>>(
      htc_hi, htc_lo, 1024, 1048576L,
      mbS_hi, mbS_lo, 1024, 2097152L,
      1024, lens,
      alignBuf, nullptr, nullptr, 2048, 2097152L,
      4, 7, 2048);

  // masked softmax; P f32 -> d_out[1], P fp16 packed in place over alignBuf rows
  softmax_k<<<dim3(16384), blk, 0, stream>>>(alignBuf, lens, out + 16777216L);

  // mbT from split bf16 (hi+lo recombine -> fp16), into srcU region (dead after G1)
  transpose2_k<<<dim3(32, 16, 16), blk, 0, stream>>>(mbS_hi, mbS_lo, mbT);
  // then overwrite mbS_hi region (dead after transpose2) with fp16 copies
  copy_f16_k<<<dim3(16384), blk, 0, stream>>>(src, srcF16, 4194304L);
  copy_f16_k<<<dim3(2048),  blk, 0, stream>>>(Wo,  Wo_f16, 524288L);

  // G3: c[b] = P[b] @ mbT[b]^T  (M=1024,N=1024,K=2048)x16, fp16 1-prod, fp16 store, maskK
  gemmW<3, 2><<<dim3(512), dim3(512), 0, stream>>>(
      (const u16*)alignBuf, (const u16*)alignBuf, 1 << 30, 4096, 4194304L,
      mbT, 2048, 2097152L,
      2048, lens,
      nullptr, htc_hi, 1024, 1048576L,
      3, 5, 512);

  // G4: attn = tanh([c,src] @ Wo^T)  (M=16384,N=1024,K=2048), fp16 1-prod, tanh+transpose store
  gemmW<2, 0><<<dim3(512), dim3(512), 0, stream>>>(
      htc_hi, srcF16, 1024, 1024, 0L,
      Wo_f16, 2048, 0L,
      2048, lens,
      out, nullptr, 1024, 0L,
      3, 9, 512);
}

// Round 15
// 813.104 us; speedup vs baseline: 1.0643x; 1.0643x over previous
//
#include <hip/hip_runtime.h>

typedef __attribute__((ext_vector_type(8))) short s16x8;
typedef __attribute__((ext_vector_type(8))) _Float16 f16x8;
typedef __attribute__((ext_vector_type(4))) float f32x4;
typedef __attribute__((ext_vector_type(4))) unsigned short u16x4;
typedef unsigned short u16;

// ---------- bf16 helpers (RNE) ----------
__device__ __forceinline__ u16 f2bf(float x) {
  unsigned u = __builtin_bit_cast(unsigned, x);
  u = u + 0x7fffu + ((u >> 16) & 1u);
  return (u16)(u >> 16);
}
__device__ __forceinline__ float bf2f(u16 h) {
  return __builtin_bit_cast(float, (unsigned)h << 16);
}
__device__ __forceinline__ void split_bf(float x, u16 &h, u16 &l) {
  h = f2bf(x); l = f2bf(x - bf2f(h));
}
__device__ __forceinline__ u16 f2h(float x) {
  return __builtin_bit_cast(u16, (_Float16)x);
}

// ---------- async global -> LDS, 16B per lane ----------
typedef __attribute__((address_space(1))) const unsigned int as1c_u32;
typedef __attribute__((address_space(3))) unsigned int as3_u32;
__device__ __forceinline__ void gload16(const void* g, void* l) {
  __builtin_amdgcn_global_load_lds((as1c_u32*)g, (as3_u32*)l, 16, 0, 0);
}

// ---------- vectorized split: f32 -> hi/lo bf16 ----------
__global__ __launch_bounds__(256) void split_copy_k(
    const float* __restrict__ in, u16* __restrict__ oh, u16* __restrict__ ol, long n4) {
  const long i = (long)blockIdx.x * 256 + threadIdx.x;
  if (i >= n4) return;
  const f32x4 v = *(const f32x4*)(in + i * 4);
  u16x4 h, l;
#pragma unroll
  for (int e = 0; e < 4; ++e) { u16 hh, ll; split_bf(v[e], hh, ll); h[e] = hh; l[e] = ll; }
  *(u16x4*)(oh + i * 4) = h;
  *(u16x4*)(ol + i * 4) = l;
}

// ---------- f32 -> fp16 copy ----------
__global__ __launch_bounds__(256) void copy_f16_k(
    const float* __restrict__ in, u16* __restrict__ oh, long n4) {
  const long i = (long)blockIdx.x * 256 + threadIdx.x;
  if (i >= n4) return;
  const f32x4 v = *(const f32x4*)(in + i * 4);
  u16x4 h;
#pragma unroll
  for (int e = 0; e < 4; ++e) h[e] = f2h(v[e]);
  *(u16x4*)(oh + i * 4) = h;
}

// ---------- transpose from split bf16: mbS hi/lo [b][S=2048][D=1024] -> mbT [b][D][S] fp16 ----------
__global__ __launch_bounds__(256) void transpose2_k(
    const u16* __restrict__ inh, const u16* __restrict__ inl, u16* __restrict__ outT) {
  __shared__ u16 th[64][72], tl[64][72];
  const int b = blockIdx.z;
  const int s0 = blockIdx.x * 64, d0 = blockIdx.y * 64;
  const long base = (long)b * 2048 * 1024;
  const int t = threadIdx.x;
#pragma unroll
  for (int i = 0; i < 4; ++i) {
    const int idx = i * 256 + t;
    const int r = idx >> 4;          // s-row 0..63
    const int c4 = (idx & 15) * 4;   // d quad
    const long o = base + (long)(s0 + r) * 1024 + d0 + c4;
    *(u16x4*)&th[r][c4] = *(const u16x4*)&inh[o];
    *(u16x4*)&tl[r][c4] = *(const u16x4*)&inl[o];
  }
  __syncthreads();
  u16* pout = outT + (long)b * 1024 * 2048;
#pragma unroll
  for (int i = 0; i < 4; ++i) {
    const int idx = i * 256 + t;
    const int r = idx >> 4;          // d-row 0..63
    const int c4 = (idx & 15) * 4;   // s quad
    u16x4 v;
#pragma unroll
    for (int e = 0; e < 4; ++e)
      v[e] = f2h(bf2f(th[c4 + e][r]) + bf2f(tl[c4 + e][r]));
    *(u16x4*)&pout[(long)(d0 + r) * 2048 + s0 + c4] = v;
  }
}

// ---------- masked softmax over S=2048; P f32 -> out [T,B,S]; P fp16 packed in place ----------
__global__ __launch_bounds__(256) void softmax_k(
    float* __restrict__ alignBuf, const int* __restrict__ lens, float* __restrict__ outP) {
  const int row = blockIdx.x;          // b*1024 + t
  const int b = row >> 10;
  const int tt = row & 1023;
  const int len = lens[b];
  float* arow = alignBuf + (long)row * 2048;
  const int t = threadIdx.x;
  const int lane = t & 63, wv = t >> 6;
  float v[8];
  float mx = -3.0e38f;
#pragma unroll
  for (int j = 0; j < 8; ++j) {
    const int s = j * 256 + t;
    const float x = (s < len) ? arow[s] : -1.0e9f;   // skip masked loads
    v[j] = x;
    mx = fmaxf(mx, x);
  }
#pragma unroll
  for (int off = 32; off; off >>= 1) mx = fmaxf(mx, __shfl_xor(mx, off));
  __shared__ float redm[4], reds[4];
  if (lane == 0) redm[wv] = mx;
  __syncthreads();
  mx = fmaxf(fmaxf(redm[0], redm[1]), fmaxf(redm[2], redm[3]));
  float e[8]; float sum = 0.f;
#pragma unroll
  for (int j = 0; j < 8; ++j) { e[j] = __expf(v[j] - mx); sum += e[j]; }
#pragma unroll
  for (int off = 32; off; off >>= 1) sum += __shfl_xor(sum, off);
  if (lane == 0) reds[wv] = sum;
  __syncthreads();   // fences all reads of arow before in-place overwrite below
  sum = reds[0] + reds[1] + reds[2] + reds[3];
  const float inv = 1.0f / sum;
  u16* ph = (u16*)arow;          // [0,2048): P fp16 (first 4KB of the 8KB row)
  float* orow = outP + ((long)tt * 16 + b) * 2048;
#pragma unroll
  for (int j = 0; j < 8; ++j) {
    const int s = j * 256 + t;
    const float pv = e[j] * inv;
    orow[s] = pv;
    ph[s] = f2h(pv);             // exact 0 beyond len -> maskK in G3 exact
  }
}

// ========== Template A: 128x128, BK=32, single-buf, glds (G1/G2, bf16 3-prod) ==========
// EP: 0 = f32 Cf; 1 = split bf16 Ch/Cl. MASK: 0 none; 1 = exit block if n0 >= lens[bz].
template<int NPROD, int EP, int MASK>
__global__ __launch_bounds__(256) void gemm128(
    const u16* __restrict__ Ah, const u16* __restrict__ Al,
    const u16* __restrict__ Ah2, const u16* __restrict__ Al2,
    int kSplitA, int lda, long sA,
    const u16* __restrict__ Bh, const u16* __restrict__ Bl, int ldb, long sB,
    int K, const int* __restrict__ lens,
    float* __restrict__ Cf, u16* __restrict__ Ch, u16* __restrict__ Cl,
    int ldc, long sC, int lgx, int lgxy, int nwg) {
  constexpr int NT = (NPROD >= 3) ? 4 : (NPROD == 2 ? 3 : 2);
  __shared__ __align__(16) u16 lds[NT][4096];   // [kc(4)][row(128)][8]

  const int orig = blockIdx.x;
  const int wg = (orig & 7) * (nwg >> 3) + (orig >> 3);
  const int bx = wg & ((1 << lgx) - 1);
  const int by = (wg >> lgx) & ((1 << (lgxy - lgx)) - 1);
  const int bz = wg >> lgxy;

  const long m0 = (long)by * 128;
  const long n0 = (long)bx * 128;

  if constexpr (MASK == 1) {
    if (n0 >= lens[bz]) return;        // block-uniform, before any barrier
  }

  const u16* pAh  = Ah  + (long)bz * sA;
  const u16* pAl  = Al  + (long)bz * sA;
  const u16* pAh2 = Ah2 + (long)bz * sA;
  const u16* pAl2 = Al2 + (long)bz * sA;
  const u16* pBh  = Bh  + (long)bz * sB;
  const u16* pBl  = Bl  + (long)bz * sB;

  const int t = threadIdx.x;
  const int lane = t & 63;
  const int wv = t >> 6;
  const int wm = wv >> 1;
  const int wn = wv & 1;
  const int lk = lane >> 4;
  const int lr = lane & 15;

  f32x4 acc[4][4];
#pragma unroll
  for (int i = 0; i < 4; ++i)
#pragma unroll
    for (int j = 0; j < 4; ++j) acc[i][j] = 0.0f;

  for (int k0 = 0; k0 < K; k0 += 32) {
    __syncthreads();
#pragma unroll
    for (int j = 0; j < 2; ++j) {
      const int ci = (j * 4 + wv) * 64;   // wave-uniform entry base
      const int c = ci + lane;
      const int kc = c >> 7;
      const int r = c & 127;
      const int k = k0 + kc * 8;
      const u16 *aH = pAh, *aL = pAl;
      long ka = k;
      if (k >= kSplitA) { aH = pAh2; aL = pAl2; ka = k - kSplitA; }
      const long aoff = (m0 + r) * (long)lda + ka;
      gload16(aH + aoff, &lds[0][ci * 8]);
      if constexpr (NPROD >= 2) gload16(aL + aoff, &lds[2][ci * 8]);
      const long boff = (n0 + r) * (long)ldb + k;
      gload16(pBh + boff, &lds[1][ci * 8]);
      if constexpr (NPROD >= 3) gload16(pBl + boff, &lds[3][ci * 8]);
    }
    __syncthreads();

    s16x8 ah[4], al[4], bh[4], bl[4];
#pragma unroll
    for (int f = 0; f < 4; ++f) {
      const int ra = wm * 64 + f * 16 + lr;
      const int rb = wn * 64 + f * 16 + lr;
      ah[f] = *(const s16x8*)&lds[0][lk * 1024 + ra * 8];
      bh[f] = *(const s16x8*)&lds[1][lk * 1024 + rb * 8];
      if constexpr (NPROD >= 2) al[f] = *(const s16x8*)&lds[2][lk * 1024 + ra * 8];
      if constexpr (NPROD >= 3) bl[f] = *(const s16x8*)&lds[3][lk * 1024 + rb * 8];
    }
#pragma unroll
    for (int i = 0; i < 4; ++i)
#pragma unroll
      for (int j = 0; j < 4; ++j) {
        acc[i][j] = __builtin_amdgcn_mfma_f32_16x16x32_bf16(ah[i], bh[j], acc[i][j], 0, 0, 0);
        if constexpr (NPROD >= 3)
          acc[i][j] = __builtin_amdgcn_mfma_f32_16x16x32_bf16(ah[i], bl[j], acc[i][j], 0, 0, 0);
        if constexpr (NPROD >= 2)
          acc[i][j] = __builtin_amdgcn_mfma_f32_16x16x32_bf16(al[i], bh[j], acc[i][j], 0, 0, 0);
      }
  }

#pragma unroll
  for (int fm = 0; fm < 4; ++fm)
#pragma unroll
    for (int fn = 0; fn < 4; ++fn)
#pragma unroll
      for (int r = 0; r < 4; ++r) {
        const long row = m0 + wm * 64 + fm * 16 + (lane >> 4) * 4 + r;
        const long col = n0 + wn * 64 + fn * 16 + lr;
        const float v = acc[fm][fn][r];
        if constexpr (EP == 0) {
          Cf[(long)bz * sC + row * ldc + col] = v;
        } else if constexpr (EP == 1) {
          u16 h, l; split_bf(v, h, l);
          const long o = (long)bz * sC + row * ldc + col;
          Ch[o] = h; Cl[o] = l;
        }
      }
}

// ========== Template W: 256x128 tile, BK=64, 512 thr (8 waves: 4m x 2n), fp16 1-prod ==========
// A 256xK fp16, optional switch to A2 at kSplitA (concat trick); B 128xK fp16.
// EP: 2 = tanh + [T,B,D] transposed f32 store; 3 = fp16 C store.
// MASK: 0 none; 2 = truncate K at ceil(lens[bz]/64)*64.
template<int EP, int MASK>
__global__ __launch_bounds__(512) void gemmW(
    const u16* __restrict__ A1, const u16* __restrict__ A2, int kSplitA, int lda, long sA,
    const u16* __restrict__ B, int ldb, long sB,
    int K, const int* __restrict__ lens,
    float* __restrict__ Cf, u16* __restrict__ Ch,
    int ldc, long sC, int lgx, int lgxy, int nwg) {
  __shared__ __align__(16) u16 ldsA[16384];  // [kc(8)][row(256)][8]  32KB
  __shared__ __align__(16) u16 ldsB[8192];   // [kc(8)][row(128)][8]  16KB

  const int orig = blockIdx.x;
  const int wg = (orig & 7) * (nwg >> 3) + (orig >> 3);
  const int bx = wg & ((1 << lgx) - 1);
  const int by = (wg >> lgx) & ((1 << (lgxy - lgx)) - 1);
  const int bz = wg >> lgxy;

  const long m0 = (long)by * 256;
  const long n0 = (long)bx * 128;

  int Klim = K;
  if constexpr (MASK == 2) {
    const int kl = (lens[bz] + 63) & ~63;
    Klim = kl < K ? kl : K;
  }

  const u16* pA1 = A1 + (long)bz * sA;
  const u16* pA2 = A2 + (long)bz * sA;
  const u16* pB  = B  + (long)bz * sB;

  const int t = threadIdx.x;
  const int lane = t & 63;
  const int wv = t >> 6;        // 0..7
  const int wm = wv >> 1;       // 0..3  (M quarter, 64 rows)
  const int wn = wv & 1;        // 0..1  (N half, 64 cols)
  const int lk = lane >> 4;     // 0..3
  const int lr = lane & 15;

  f32x4 acc[4][4];
#pragma unroll
  for (int i = 0; i < 4; ++i)
#pragma unroll
    for (int j = 0; j < 4; ++j) acc[i][j] = 0.0f;

  for (int k0 = 0; k0 < Klim; k0 += 64) {
    __syncthreads();
    // stage A 256x64 (2048 entries of 8 halves), 4 chunks/lane
#pragma unroll
    for (int j = 0; j < 4; ++j) {
      const int ci = (j * 8 + wv) * 64;   // 64-aligned -> kc uniform in chunk
      const int c = ci + lane;
      const int kc = c >> 8;              // 0..7
      const int r = c & 255;
      const int k = k0 + kc * 8;
      const u16* a = pA1; long ka = k;
      if (k >= kSplitA) { a = pA2; ka = k - kSplitA; }
      gload16(a + (m0 + r) * (long)lda + ka, &ldsA[ci * 8]);
    }
    // stage B 128x64 (1024 entries), 2 chunks/lane
#pragma unroll
    for (int j = 0; j < 2; ++j) {
      const int ci = (j * 8 + wv) * 64;
      const int c = ci + lane;
      const int kc = c >> 7;              // 0..7
      const int r = c & 127;
      const int k = k0 + kc * 8;
      gload16(pB + (n0 + r) * (long)ldb + k, &ldsB[ci * 8]);
    }
    __syncthreads();

#pragma unroll
    for (int ks = 0; ks < 2; ++ks) {
      const int kc = ks * 4 + lk;         // 0..7
      f16x8 a[4], b[4];
#pragma unroll
      for (int f = 0; f < 4; ++f) {
        const int ra = wm * 64 + f * 16 + lr;
        const int rb = wn * 64 + f * 16 + lr;
        a[f] = *(const f16x8*)&ldsA[(kc * 256 + ra) * 8];
        b[f] = *(const f16x8*)&ldsB[(kc * 128 + rb) * 8];
      }
#pragma unroll
      for (int i = 0; i < 4; ++i)
#pragma unroll
        for (int j = 0; j < 4; ++j)
          acc[i][j] = __builtin_amdgcn_mfma_f32_16x16x32_f16(a[i], b[j], acc[i][j], 0, 0, 0);
    }
  }

#pragma unroll
  for (int fm = 0; fm < 4; ++fm)
#pragma unroll
    for (int fn = 0; fn < 4; ++fn)
#pragma unroll
      for (int r = 0; r < 4; ++r) {
        const long row = m0 + wm * 64 + fm * 16 + (lane >> 4) * 4 + r;
        const long col = n0 + wn * 64 + fn * 16 + lr;
        const float v = acc[fm][fn][r];
        if constexpr (EP == 2) {
          const long bb = row >> 10;       // batch (T=1024)
          const long tt = row & 1023;      // t
          Cf[(tt * 16 + bb) * (long)ldc + col] = tanhf(v);
        } else {
          Ch[(long)bz * sC + row * ldc + col] = f2h(v);
        }
      }
}

extern "C" void kernel_launch(void* const* d_in, const int* in_sizes, int n_in,
                              void* d_out, int out_size, void* d_ws, size_t ws_size,
                              hipStream_t stream) {
  (void)in_sizes; (void)n_in; (void)out_size; (void)ws_size;
  const float* src = (const float*)d_in[0];   // [16,1024,1024]
  const float* mb  = (const float*)d_in[1];   // [16,2048,1024]
  const int*   lens= (const int*)d_in[2];     // [16]
  const float* Wi  = (const float*)d_in[3];   // [1024,1024]
  const float* Wo  = (const float*)d_in[4];   // [1024,2048]
  float* out = (float*)d_out;                 // attn [T,B,D] f32, then P [T,B,S] f32

  // workspace (384 MiB) — round-12 proven layout
  char* p = (char*)d_ws;
  u16* mbS_hi  = (u16*)p;                         // 64 MiB (read by G2+transpose2, then -> srcF16/Wo_f16)
  u16* mbS_lo  = (u16*)(p + (64L << 20));         // 64 MiB (read by G2+transpose2, then dead)
  u16* srcU_hi = (u16*)(p + (128L << 20));        // 32 MiB bf16 (G1; dead after -> mbT)
  u16* srcU_lo = (u16*)(p + (160L << 20));        // 32 MiB bf16 (G1; dead after -> mbT)
  u16* htc_hi  = (u16*)(p + (192L << 20));        // 32 MiB h_t hi -> c fp16 (G3 out)
  u16* htc_lo  = (u16*)(p + (224L << 20));        // 32 MiB h_t lo (dead after G2)
  float* alignBuf = (float*)(p + (256L << 20));   // 128 MiB [16][1024][2048] f32
  u16* Wi_hi = (u16*)alignBuf;                    // borrow head of alignBuf pre-G2
  u16* Wi_lo = Wi_hi + 1048576;
  u16* mbT    = srcU_hi;                          // [b][D][S] fp16, 64 MiB = srcU region exactly
  u16* srcF16 = mbS_hi;                           // 32 MiB (16384x1024 fp16), after transpose2 read
  u16* Wo_f16 = mbS_hi + 16777216;                // 4 MiB at +32 MiB

  dim3 blk(256);
  split_copy_k<<<dim3(32768), blk, 0, stream>>>(mb,  mbS_hi, mbS_lo, 8388608L);
  split_copy_k<<<dim3(16384), blk, 0, stream>>>(src, srcU_hi, srcU_lo, 4194304L);
  split_copy_k<<<dim3(1024),  blk, 0, stream>>>(Wi,  Wi_hi,  Wi_lo,  262144L);

  // G1: h_t = src @ Wi^T  (M=16384,N=1024,K=1024), bf16 3-prod, split store
  gemm128<3, 1, 0><<<dim3(1024), blk, 0, stream>>>(
      srcU_hi, srcU_lo, srcU_hi, srcU_lo, 1 << 30, 1024, 0L,
      Wi_hi, Wi_lo, 1024, 0L,
      1024, lens,
      nullptr, htc_hi, htc_lo, 1024, 0L,
      3, 10, 1024);

  // G2: align[b] = h_t[b] @ mb[b]^T  (M=1024,N=2048,K=1024)x16, bf16 3-prod, f32 store, maskN
  gemm128<3, 0, 1><<<dim3(2048), blk, 0, stream>>>(
      htc_hi, htc_lo, htc_hi, htc_lo, 1 << 30, 1024, 1048576L,
      mbS_hi, mbS_lo, 1024, 2097152L,
      1024, lens,
      alignBuf, nullptr, nullptr, 2048, 2097152L,
      4, 7, 2048);

  // masked softmax; P f32 -> d_out[1], P fp16 packed in place over alignBuf rows
  softmax_k<<<dim3(16384), blk, 0, stream>>>(alignBuf, lens, out + 16777216L);

  // mbT from split bf16 (hi+lo recombine -> fp16), into srcU region (dead after G1)
  transpose2_k<<<dim3(32, 16, 16), blk, 0, stream>>>(mbS_hi, mbS_lo, mbT);
  // then overwrite mbS_hi region (dead after transpose2) with fp16 copies
  copy_f16_k<<<dim3(16384), blk, 0, stream>>>(src, srcF16, 4194304L);
  copy_f16_k<<<dim3(2048),  blk, 0, stream>>>(Wo,  Wo_f16, 524288L);

  // G3: c[b] = P[b] @ mbT[b]^T  (M=1024,N=1024,K=2048)x16, fp16 1-prod, fp16 store, maskK
  gemmW<3, 2><<<dim3(512), dim3(512), 0, stream>>>(
      (const u16*)alignBuf, (const u16*)alignBuf, 1 << 30, 4096, 4194304L,
      mbT, 2048, 2097152L,
      2048, lens,
      nullptr, htc_hi, 1024, 1048576L,
      3, 5, 512);

  // G4: attn = tanh([c,src] @ Wo^T)  (M=16384,N=1024,K=2048), fp16 1-prod, tanh+transpose store
  gemmW<2, 0><<<dim3(512), dim3(512), 0, stream>>>(
      htc_hi, srcF16, 1024, 1024, 0L,
      Wo_f16, 2048, 0L,
      2048, lens,
      out, nullptr, 1024, 0L,
      3, 9, 512);
}

// Round 16
// 808.659 us; speedup vs baseline: 1.0701x; 1.0055x over previous
//
#include <hip/hip_runtime.h>

typedef __attribute__((ext_vector_type(8))) short s16x8;
typedef __attribute__((ext_vector_type(8))) unsigned short u16x8;
typedef __attribute__((ext_vector_type(8))) _Float16 f16x8;
typedef __attribute__((ext_vector_type(4))) float f32x4;
typedef __attribute__((ext_vector_type(4))) unsigned short u16x4;
typedef unsigned short u16;

// ---------- bf16 helpers (RNE) ----------
__device__ __forceinline__ u16 f2bf(float x) {
  unsigned u = __builtin_bit_cast(unsigned, x);
  u = u + 0x7fffu + ((u >> 16) & 1u);
  return (u16)(u >> 16);
}
__device__ __forceinline__ float bf2f(u16 h) {
  return __builtin_bit_cast(float, (unsigned)h << 16);
}
__device__ __forceinline__ void split_bf(float x, u16 &h, u16 &l) {
  h = f2bf(x); l = f2bf(x - bf2f(h));
}
__device__ __forceinline__ u16 f2h(float x) {
  return __builtin_bit_cast(u16, (_Float16)x);
}

// ---------- async global -> LDS, 16B per lane (G3/G4 engine) ----------
typedef __attribute__((address_space(1))) const unsigned int as1c_u32;
typedef __attribute__((address_space(3))) unsigned int as3_u32;
__device__ __forceinline__ void gload16(const void* g, void* l) {
  __builtin_amdgcn_global_load_lds((as1c_u32*)g, (as3_u32*)l, 16, 0, 0);
}

// ---------- vectorized split: f32 -> hi/lo bf16 ----------
__global__ __launch_bounds__(256) void split_copy_k(
    const float* __restrict__ in, u16* __restrict__ oh, u16* __restrict__ ol, long n4) {
  const long i = (long)blockIdx.x * 256 + threadIdx.x;
  if (i >= n4) return;
  const f32x4 v = *(const f32x4*)(in + i * 4);
  u16x4 h, l;
#pragma unroll
  for (int e = 0; e < 4; ++e) { u16 hh, ll; split_bf(v[e], hh, ll); h[e] = hh; l[e] = ll; }
  *(u16x4*)(oh + i * 4) = h;
  *(u16x4*)(ol + i * 4) = l;
}

// ---------- f32 -> fp16 copy ----------
__global__ __launch_bounds__(256) void copy_f16_k(
    const float* __restrict__ in, u16* __restrict__ oh, long n4) {
  const long i = (long)blockIdx.x * 256 + threadIdx.x;
  if (i >= n4) return;
  const f32x4 v = *(const f32x4*)(in + i * 4);
  u16x4 h;
#pragma unroll
  for (int e = 0; e < 4; ++e) h[e] = f2h(v[e]);
  *(u16x4*)(oh + i * 4) = h;
}

// ---------- transpose to fp16: mb [b][S=2048][D=1024] f32 -> mbT [b][D][S] fp16 (round-10 proven) ----------
__global__ __launch_bounds__(256) void transpose_f16_k(
    const float* __restrict__ in, u16* __restrict__ oh) {
  __shared__ float tile[64][65];
  const int b = blockIdx.z;
  const int s0 = blockIdx.x * 64, d0 = blockIdx.y * 64;
  const float* pin = in + (long)b * 2048 * 1024;
  const int t = threadIdx.x;
#pragma unroll
  for (int i = 0; i < 16; ++i) {
    const int idx = i * 256 + t;
    const int r = idx >> 6, c = idx & 63;
    tile[r][c] = pin[(long)(s0 + r) * 1024 + d0 + c];
  }
  __syncthreads();
  u16* poh = oh + (long)b * 1024 * 2048;
#pragma unroll
  for (int i = 0; i < 16; ++i) {
    const int idx = i * 256 + t;
    const int r = idx >> 6, c = idx & 63;   // r: d, c: s
    poh[(long)(d0 + r) * 2048 + s0 + c] = f2h(tile[c][r]);
  }
}

// ---------- masked softmax over S=2048; P f32 -> out [T,B,S]; P fp16 packed in place ----------
__global__ __launch_bounds__(256) void softmax_k(
    float* __restrict__ alignBuf, const int* __restrict__ lens, float* __restrict__ outP) {
  const int row = blockIdx.x;          // b*1024 + t
  const int b = row >> 10;
  const int tt = row & 1023;
  const int len = lens[b];
  float* arow = alignBuf + (long)row * 2048;
  const int t = threadIdx.x;
  const int lane = t & 63, wv = t >> 6;
  float v[8];
  float mx = -3.0e38f;
#pragma unroll
  for (int j = 0; j < 8; ++j) {
    const int s = j * 256 + t;
    const float x = (s < len) ? arow[s] : -1.0e9f;   // skip masked loads
    v[j] = x;
    mx = fmaxf(mx, x);
  }
#pragma unroll
  for (int off = 32; off; off >>= 1) mx = fmaxf(mx, __shfl_xor(mx, off));
  __shared__ float redm[4], reds[4];
  if (lane == 0) redm[wv] = mx;
  __syncthreads();
  mx = fmaxf(fmaxf(redm[0], redm[1]), fmaxf(redm[2], redm[3]));
  float e[8]; float sum = 0.f;
#pragma unroll
  for (int j = 0; j < 8; ++j) { e[j] = __expf(v[j] - mx); sum += e[j]; }
#pragma unroll
  for (int off = 32; off; off >>= 1) sum += __shfl_xor(sum, off);
  if (lane == 0) reds[wv] = sum;
  __syncthreads();   // fences all reads of arow before in-place overwrite below
  sum = reds[0] + reds[1] + reds[2] + reds[3];
  const float inv = 1.0f / sum;
  u16* ph = (u16*)arow;          // [0,2048): P fp16 (first 4KB of the 8KB row)
  float* orow = outP + ((long)tt * 16 + b) * 2048;
#pragma unroll
  for (int j = 0; j < 8; ++j) {
    const int s = j * 256 + t;
    const float pv = e[j] * inv;
    orow[s] = pv;
    ph[s] = f2h(pv);             // exact 0 beyond len -> maskK in G3 exact
  }
}

// ========== Template R (round-1-proven engine): 128x128, BK=32, 4 waves, reg-staged, bf16 3-prod ==========
// C[m,n] = sum_k A[m,k]*B[n,k]; A pre-split bf16 hi/lo; B split ON-THE-FLY from f32.
// 566 TF measured (round 1: VGPR 76, occupancy 29%). EP: 0 = f32 C; 1 = split bf16 hi/lo C.
// MASK: 0 none; 1 = exit block if n0 >= lens[bz].
template<int EP, int MASK>
__global__ __launch_bounds__(256, 2) void gemmR(
    const u16* __restrict__ Ah, const u16* __restrict__ Al, int lda, long sA,
    const float* __restrict__ Bf, int ldb, long sB,
    int K, const int* __restrict__ lens,
    float* __restrict__ Cf, u16* __restrict__ Ch, u16* __restrict__ Cl,
    int ldc, long sC, int lgx, int lgxy, int nwg) {
  __shared__ __align__(16) u16 ldsA[2][4096];   // [hi/lo][ [kc(4)][row(128)][8] ]
  __shared__ __align__(16) u16 ldsB[2][4096];

  // bijective XCD swizzle (nwg % 8 == 0 for our launches)
  const int orig = blockIdx.x;
  const int wg = (orig & 7) * (nwg >> 3) + (orig >> 3);
  const int bx = wg & ((1 << lgx) - 1);
  const int by = (wg >> lgx) & ((1 << (lgxy - lgx)) - 1);
  const int bz = wg >> lgxy;

  const long m0 = (long)by * 128;
  const long n0 = (long)bx * 128;

  if constexpr (MASK == 1) {
    if (n0 >= lens[bz]) return;        // block-uniform, before any barrier
  }

  const u16* pAh = Ah + (long)bz * sA;
  const u16* pAl = Al + (long)bz * sA;
  const float* pBf = Bf + (long)bz * sB;

  const int t = threadIdx.x;
  const int lane = t & 63;
  const int wv = t >> 6;
  const int wm = wv >> 1;
  const int wn = wv & 1;
  const int lk = lane >> 4;
  const int lr = lane & 15;
  const int fragBase = lk * 1024;

  f32x4 acc[4][4];
#pragma unroll
  for (int i = 0; i < 4; ++i)
#pragma unroll
    for (int j = 0; j < 4; ++j) acc[i][j] = 0.0f;

  for (int k0 = 0; k0 < K; k0 += 32) {
    __syncthreads();
    // stage 128x32 hi/lo tiles for A (pre-split) and B (on-the-fly from f32), layout [kc][row][8]
#pragma unroll
    for (int j = 0; j < 2; ++j) {
      const int c = j * 256 + t;
      const int kc = c >> 7, r = c & 127;
      const int k = k0 + kc * 8;
      const long aoff = (m0 + r) * (long)lda + k;
      *(u16x8*)&ldsA[0][c * 8] = *(const u16x8*)(pAh + aoff);
      *(u16x8*)&ldsA[1][c * 8] = *(const u16x8*)(pAl + aoff);
      const float* s = pBf + (n0 + r) * (long)ldb + k;
      u16x8 bh, bl;
#pragma unroll
      for (int e = 0; e < 8; ++e) { u16 hh, ll; split_bf(s[e], hh, ll); bh[e] = hh; bl[e] = ll; }
      *(u16x8*)&ldsB[0][c * 8] = bh;
      *(u16x8*)&ldsB[1][c * 8] = bl;
    }
    __syncthreads();

    s16x8 ah[4], al[4], bh[4], bl[4];
#pragma unroll
    for (int f = 0; f < 4; ++f) {
      const int ra = wm * 64 + f * 16 + lr;
      const int rb = wn * 64 + f * 16 + lr;
      ah[f] = *(const s16x8*)&ldsA[0][fragBase + ra * 8];
      al[f] = *(const s16x8*)&ldsA[1][fragBase + ra * 8];
      bh[f] = *(const s16x8*)&ldsB[0][fragBase + rb * 8];
      bl[f] = *(const s16x8*)&ldsB[1][fragBase + rb * 8];
    }
#pragma unroll
    for (int i = 0; i < 4; ++i)
#pragma unroll
      for (int j = 0; j < 4; ++j) {
        acc[i][j] = __builtin_amdgcn_mfma_f32_16x16x32_bf16(ah[i], bh[j], acc[i][j], 0, 0, 0);
        acc[i][j] = __builtin_amdgcn_mfma_f32_16x16x32_bf16(ah[i], bl[j], acc[i][j], 0, 0, 0);
        acc[i][j] = __builtin_amdgcn_mfma_f32_16x16x32_bf16(al[i], bh[j], acc[i][j], 0, 0, 0);
      }
  }

  // epilogue; C/D frag: col = lane&15, row = (lane>>4)*4 + reg  [verified all rounds]
#pragma unroll
  for (int fm = 0; fm < 4; ++fm)
#pragma unroll
    for (int fn = 0; fn < 4; ++fn)
#pragma unroll
      for (int r = 0; r < 4; ++r) {
        const long row = m0 + wm * 64 + fm * 16 + (lane >> 4) * 4 + r;
        const long col = n0 + wn * 64 + fn * 16 + lr;
        const float v = acc[fm][fn][r];
        if constexpr (EP == 0) {
          Cf[(long)bz * sC + row * ldc + col] = v;
        } else {
          u16 h, l; split_bf(v, h, l);
          const long o = (long)bz * sC + row * ldc + col;
          Ch[o] = h; Cl[o] = l;
        }
      }
}

// ========== Template W: 256x128 tile, BK=64, 512 thr (8 waves: 4m x 2n), fp16 1-prod ==========
// A 256xK fp16, optional switch to A2 at kSplitA (concat trick); B 128xK fp16.
// EP: 2 = tanh + [T,B,D] transposed f32 store; 3 = fp16 C store.
// MASK: 0 none; 2 = truncate K at ceil(lens[bz]/64)*64.
template<int EP, int MASK>
__global__ __launch_bounds__(512) void gemmW(
    const u16* __restrict__ A1, const u16* __restrict__ A2, int kSplitA, int lda, long sA,
    const u16* __restrict__ B, int ldb, long sB,
    int K, const int* __restrict__ lens,
    float* __restrict__ Cf, u16* __restrict__ Ch,
    int ldc, long sC, int lgx, int lgxy, int nwg) {
  __shared__ __align__(16) u16 ldsA[16384];  // [kc(8)][row(256)][8]  32KB
  __shared__ __align__(16) u16 ldsB[8192];   // [kc(8)][row(128)][8]  16KB

  const int orig = blockIdx.x;
  const int wg = (orig & 7) * (nwg >> 3) + (orig >> 3);
  const int bx = wg & ((1 << lgx) - 1);
  const int by = (wg >> lgx) & ((1 << (lgxy - lgx)) - 1);
  const int bz = wg >> lgxy;

  const long m0 = (long)by * 256;
  const long n0 = (long)bx * 128;

  int Klim = K;
  if constexpr (MASK == 2) {
    const int kl = (lens[bz] + 63) & ~63;
    Klim = kl < K ? kl : K;
  }

  const u16* pA1 = A1 + (long)bz * sA;
  const u16* pA2 = A2 + (long)bz * sA;
  const u16* pB  = B  + (long)bz * sB;

  const int t = threadIdx.x;
  const int lane = t & 63;
  const int wv = t >> 6;        // 0..7
  const int wm = wv >> 1;       // 0..3  (M quarter, 64 rows)
  const int wn = wv & 1;        // 0..1  (N half, 64 cols)
  const int lk = lane >> 4;     // 0..3
  const int lr = lane & 15;

  f32x4 acc[4][4];
#pragma unroll
  for (int i = 0; i < 4; ++i)
#pragma unroll
    for (int j = 0; j < 4; ++j) acc[i][j] = 0.0f;

  for (int k0 = 0; k0 < Klim; k0 += 64) {
    __syncthreads();
    // stage A 256x64 (2048 entries of 8 halves), 4 chunks/lane
#pragma unroll
    for (int j = 0; j < 4; ++j) {
      const int ci = (j * 8 + wv) * 64;   // 64-aligned -> kc uniform in chunk
      const int c = ci + lane;
      const int kc = c >> 8;              // 0..7
      const int r = c & 255;
      const int k = k0 + kc * 8;
      const u16* a = pA1; long ka = k;
      if (k >= kSplitA) { a = pA2; ka = k - kSplitA; }
      gload16(a + (m0 + r) * (long)lda + ka, &ldsA[ci * 8]);
    }
    // stage B 128x64 (1024 entries), 2 chunks/lane
#pragma unroll
    for (int j = 0; j < 2; ++j) {
      const int ci = (j * 8 + wv) * 64;
      const int c = ci + lane;
      const int kc = c >> 7;              // 0..7
      const int r = c & 127;
      const int k = k0 + kc * 8;
      gload16(pB + (n0 + r) * (long)ldb + k, &ldsB[ci * 8]);
    }
    __syncthreads();

#pragma unroll
    for (int ks = 0; ks < 2; ++ks) {
      const int kc = ks * 4 + lk;         // 0..7
      f16x8 a[4], b[4];
#pragma unroll
      for (int f = 0; f < 4; ++f) {
        const int ra = wm * 64 + f * 16 + lr;
        const int rb = wn * 64 + f * 16 + lr;
        a[f] = *(const f16x8*)&ldsA[(kc * 256 + ra) * 8];
        b[f] = *(const f16x8*)&ldsB[(kc * 128 + rb) * 8];
      }
#pragma unroll
      for (int i = 0; i < 4; ++i)
#pragma unroll
        for (int j = 0; j < 4; ++j)
          acc[i][j] = __builtin_amdgcn_mfma_f32_16x16x32_f16(a[i], b[j], acc[i][j], 0, 0, 0);
    }
  }

#pragma unroll
  for (int fm = 0; fm < 4; ++fm)
#pragma unroll
    for (int fn = 0; fn < 4; ++fn)
#pragma unroll
      for (int r = 0; r < 4; ++r) {
        const long row = m0 + wm * 64 + fm * 16 + (lane >> 4) * 4 + r;
        const long col = n0 + wn * 64 + fn * 16 + lr;
        const float v = acc[fm][fn][r];
        if constexpr (EP == 2) {
          const long bb = row >> 10;       // batch (T=1024)
          const long tt = row & 1023;      // t
          Cf[(tt * 16 + bb) * (long)ldc + col] = tanhf(v);
        } else {
          Ch[(long)bz * sC + row * ldc + col] = f2h(v);
        }
      }
}

extern "C" void kernel_launch(void* const* d_in, const int* in_sizes, int n_in,
                              void* d_out, int out_size, void* d_ws, size_t ws_size,
                              hipStream_t stream) {
  (void)in_sizes; (void)n_in; (void)out_size; (void)ws_size;
  const float* src = (const float*)d_in[0];   // [16,1024,1024]
  const float* mb  = (const float*)d_in[1];   // [16,2048,1024]
  const int*   lens= (const int*)d_in[2];     // [16]
  const float* Wi  = (const float*)d_in[3];   // [1024,1024]
  const float* Wo  = (const float*)d_in[4];   // [1024,2048]
  float* out = (float*)d_out;                 // attn [T,B,D] f32, then P [T,B,S] f32

  // workspace (320 MiB used) — no mb pre-split anymore (G2 reads f32 mb directly)
  char* p = (char*)d_ws;
  u16* srcU_hi = (u16*)p;                         // 32 MiB bf16 (G1 A; dead after G1 -> mbT)
  u16* srcU_lo = (u16*)(p + (32L << 20));         // 32 MiB bf16 (G1 A; dead after G1 -> mbT)
  u16* htc_hi  = (u16*)(p + (64L << 20));         // 32 MiB h_t hi (G1 out, G2 A) -> c fp16 (G3 out)
  u16* htc_lo  = (u16*)(p + (96L << 20));         // 32 MiB h_t lo (dead after G2)
  u16* srcF16  = (u16*)(p + (128L << 20));        // 32 MiB fp16 (G4)
  u16* Wo_f16  = (u16*)(p + (160L << 20));        // 4 MiB fp16 (G4)
  float* alignBuf = (float*)(p + (164L << 20));   // 128 MiB [16][1024][2048] f32
  u16* Wi_hi = (u16*)alignBuf;                    // borrow head of alignBuf pre-G2 (Wi read only by... )
  u16* Wi_lo = Wi_hi + 1048576;                   //   note: G1 reads Wi as f32 now; hi/lo unused — kept 0-cost
  u16* mbT   = srcU_hi;                           // [b][D][S] fp16, 64 MiB = srcU region exactly

  dim3 blk(256);
  split_copy_k<<<dim3(16384), blk, 0, stream>>>(src, srcU_hi, srcU_lo, 4194304L);
  copy_f16_k<<<dim3(16384), blk, 0, stream>>>(src, srcF16, 4194304L);
  copy_f16_k<<<dim3(2048),  blk, 0, stream>>>(Wo,  Wo_f16, 524288L);
  (void)Wi_hi; (void)Wi_lo;

  // G1: h_t = src @ Wi^T  (M=16384,N=1024,K=1024), reg-staged 3-prod, B=Wi f32 on-the-fly, split store
  gemmR<1, 0><<<dim3(1024), blk, 0, stream>>>(
      srcU_hi, srcU_lo, 1024, 0L,
      Wi, 1024, 0L,
      1024, lens,
      nullptr, htc_hi, htc_lo, 1024, 0L,
      3, 10, 1024);

  // G2: align[b] = h_t[b] @ mb[b]^T  (M=1024,N=2048,K=1024)x16, reg-staged 3-prod, B=mb f32, maskN
  gemmR<0, 1><<<dim3(2048), blk, 0, stream>>>(
      htc_hi, htc_lo, 1024, 1048576L,
      mb, 1024, 2097152L,
      1024, lens,
      alignBuf, nullptr, nullptr, 2048, 2097152L,
      4, 7, 2048);

  // masked softmax; P f32 -> d_out[1], P fp16 packed in place over alignBuf rows
  softmax_k<<<dim3(16384), blk, 0, stream>>>(alignBuf, lens, out + 16777216L);

  // mbT (fp16 transpose of f32 mb) into srcU region (dead after G1)
  transpose_f16_k<<<dim3(32, 16, 16), blk, 0, stream>>>(mb, mbT);

  // G3: c[b] = P[b] @ mbT[b]^T  (M=1024,N=1024,K=2048)x16, fp16 1-prod, fp16 store (over htc_hi), maskK
  gemmW<3, 2><<<dim3(512), dim3(512), 0, stream>>>(
      (const u16*)alignBuf, (const u16*)alignBuf, 1 << 30, 4096, 4194304L,
      mbT, 2048, 2097152L,
      2048, lens,
      nullptr, htc_hi, 1024, 1048576L,
      3, 5, 512);

  // G4: attn = tanh([c,src] @ Wo^T)  (M=16384,N=1024,K=2048), fp16 1-prod, tanh+transpose store
  gemmW<2, 0><<<dim3(512), dim3(512), 0, stream>>>(
      htc_hi, srcF16, 1024, 1024, 0L,
      Wo_f16, 2048, 0L,
      2048, lens,
      out, nullptr, 1024, 0L,
      3, 9, 512);
}

// Round 17
// 799.433 us; speedup vs baseline: 1.0825x; 1.0115x over previous
//
#include <hip/hip_runtime.h>

typedef __attribute__((ext_vector_type(8))) short s16x8;
typedef __attribute__((ext_vector_type(8))) unsigned short u16x8;
typedef __attribute__((ext_vector_type(8))) _Float16 f16x8;
typedef __attribute__((ext_vector_type(4))) float f32x4;
typedef __attribute__((ext_vector_type(4))) unsigned short u16x4;
typedef unsigned short u16;

// ---------- bf16 helpers (RNE) ----------
__device__ __forceinline__ u16 f2bf(float x) {
  unsigned u = __builtin_bit_cast(unsigned, x);
  u = u + 0x7fffu + ((u >> 16) & 1u);
  return (u16)(u >> 16);
}
__device__ __forceinline__ float bf2f(u16 h) {
  return __builtin_bit_cast(float, (unsigned)h << 16);
}
__device__ __forceinline__ void split_bf(float x, u16 &h, u16 &l) {
  h = f2bf(x); l = f2bf(x - bf2f(h));
}
__device__ __forceinline__ u16 f2h(float x) {
  return __builtin_bit_cast(u16, (_Float16)x);
}

// ---------- async global -> LDS, 16B per lane ----------
typedef __attribute__((address_space(1))) const unsigned int as1c_u32;
typedef __attribute__((address_space(3))) unsigned int as3_u32;
__device__ __forceinline__ void gload16(const void* g, void* l) {
  __builtin_amdgcn_global_load_lds((as1c_u32*)g, (as3_u32*)l, 16, 0, 0);
}

// ---------- vectorized split: f32 -> hi/lo bf16 ----------
__global__ __launch_bounds__(256) void split_copy_k(
    const float* __restrict__ in, u16* __restrict__ oh, u16* __restrict__ ol, long n4) {
  const long i = (long)blockIdx.x * 256 + threadIdx.x;
  if (i >= n4) return;
  const f32x4 v = *(const f32x4*)(in + i * 4);
  u16x4 h, l;
#pragma unroll
  for (int e = 0; e < 4; ++e) { u16 hh, ll; split_bf(v[e], hh, ll); h[e] = hh; l[e] = ll; }
  *(u16x4*)(oh + i * 4) = h;
  *(u16x4*)(ol + i * 4) = l;
}

// ---------- f32 -> fp16 copy ----------
__global__ __launch_bounds__(256) void copy_f16_k(
    const float* __restrict__ in, u16* __restrict__ oh, long n4) {
  const long i = (long)blockIdx.x * 256 + threadIdx.x;
  if (i >= n4) return;
  const f32x4 v = *(const f32x4*)(in + i * 4);
  u16x4 h;
#pragma unroll
  for (int e = 0; e < 4; ++e) h[e] = f2h(v[e]);
  *(u16x4*)(oh + i * 4) = h;
}

// ---------- transpose to fp16: mb [b][S=2048][D=1024] f32 -> mbT [b][D][S] fp16 ----------
__global__ __launch_bounds__(256) void transpose_f16_k(
    const float* __restrict__ in, u16* __restrict__ oh) {
  __shared__ float tile[64][65];
  const int b = blockIdx.z;
  const int s0 = blockIdx.x * 64, d0 = blockIdx.y * 64;
  const float* pin = in + (long)b * 2048 * 1024;
  const int t = threadIdx.x;
#pragma unroll
  for (int i = 0; i < 16; ++i) {
    const int idx = i * 256 + t;
    const int r = idx >> 6, c = idx & 63;
    tile[r][c] = pin[(long)(s0 + r) * 1024 + d0 + c];
  }
  __syncthreads();
  u16* poh = oh + (long)b * 1024 * 2048;
#pragma unroll
  for (int i = 0; i < 16; ++i) {
    const int idx = i * 256 + t;
    const int r = idx >> 6, c = idx & 63;   // r: d, c: s
    poh[(long)(d0 + r) * 2048 + s0 + c] = f2h(tile[c][r]);
  }
}

// ---------- masked softmax over S=2048; P f32 -> out [T,B,S]; P fp16 packed in place ----------
__global__ __launch_bounds__(256) void softmax_k(
    float* __restrict__ alignBuf, const int* __restrict__ lens, float* __restrict__ outP) {
  const int row = blockIdx.x;          // b*1024 + t
  const int b = row >> 10;
  const int tt = row & 1023;
  const int len = lens[b];
  float* arow = alignBuf + (long)row * 2048;
  const int t = threadIdx.x;
  const int lane = t & 63, wv = t >> 6;
  float v[8];
  float mx = -3.0e38f;
#pragma unroll
  for (int j = 0; j < 8; ++j) {
    const int s = j * 256 + t;
    const float x = (s < len) ? arow[s] : -1.0e9f;   // skip masked loads
    v[j] = x;
    mx = fmaxf(mx, x);
  }
#pragma unroll
  for (int off = 32; off; off >>= 1) mx = fmaxf(mx, __shfl_xor(mx, off));
  __shared__ float redm[4], reds[4];
  if (lane == 0) redm[wv] = mx;
  __syncthreads();
  mx = fmaxf(fmaxf(redm[0], redm[1]), fmaxf(redm[2], redm[3]));
  float e[8]; float sum = 0.f;
#pragma unroll
  for (int j = 0; j < 8; ++j) { e[j] = __expf(v[j] - mx); sum += e[j]; }
#pragma unroll
  for (int off = 32; off; off >>= 1) sum += __shfl_xor(sum, off);
  if (lane == 0) reds[wv] = sum;
  __syncthreads();   // fences all reads of arow before in-place overwrite below
  sum = reds[0] + reds[1] + reds[2] + reds[3];
  const float inv = 1.0f / sum;
  u16* ph = (u16*)arow;          // [0,2048): P fp16 (first 4KB of the 8KB row)
  float* orow = outP + ((long)tt * 16 + b) * 2048;
#pragma unroll
  for (int j = 0; j < 8; ++j) {
    const int s = j * 256 + t;
    const float pv = e[j] * inv;
    orow[s] = pv;
    ph[s] = f2h(pv);             // exact 0 beyond len -> maskK in G3 exact
  }
}

// ========== Template A (proven, G1): 128x128, BK=32, single-buf, glds, bf16 3-prod ==========
// EP: 0 = f32 Cf; 1 = split bf16 Ch/Cl. MASK: 0 none; 1 = exit block if n0 >= lens[bz].
template<int NPROD, int EP, int MASK>
__global__ __launch_bounds__(256) void gemm128(
    const u16* __restrict__ Ah, const u16* __restrict__ Al,
    const u16* __restrict__ Ah2, const u16* __restrict__ Al2,
    int kSplitA, int lda, long sA,
    const u16* __restrict__ Bh, const u16* __restrict__ Bl, int ldb, long sB,
    int K, const int* __restrict__ lens,
    float* __restrict__ Cf, u16* __restrict__ Ch, u16* __restrict__ Cl,
    int ldc, long sC, int lgx, int lgxy, int nwg) {
  constexpr int NT = (NPROD >= 3) ? 4 : (NPROD == 2 ? 3 : 2);
  __shared__ __align__(16) u16 lds[NT][4096];   // [kc(4)][row(128)][8]

  const int orig = blockIdx.x;
  const int wg = (orig & 7) * (nwg >> 3) + (orig >> 3);
  const int bx = wg & ((1 << lgx) - 1);
  const int by = (wg >> lgx) & ((1 << (lgxy - lgx)) - 1);
  const int bz = wg >> lgxy;

  const long m0 = (long)by * 128;
  const long n0 = (long)bx * 128;

  if constexpr (MASK == 1) {
    if (n0 >= lens[bz]) return;        // block-uniform, before any barrier
  }

  const u16* pAh  = Ah  + (long)bz * sA;
  const u16* pAl  = Al  + (long)bz * sA;
  const u16* pAh2 = Ah2 + (long)bz * sA;
  const u16* pAl2 = Al2 + (long)bz * sA;
  const u16* pBh  = Bh  + (long)bz * sB;
  const u16* pBl  = Bl  + (long)bz * sB;

  const int t = threadIdx.x;
  const int lane = t & 63;
  const int wv = t >> 6;
  const int wm = wv >> 1;
  const int wn = wv & 1;
  const int lk = lane >> 4;
  const int lr = lane & 15;

  f32x4 acc[4][4];
#pragma unroll
  for (int i = 0; i < 4; ++i)
#pragma unroll
    for (int j = 0; j < 4; ++j) acc[i][j] = 0.0f;

  for (int k0 = 0; k0 < K; k0 += 32) {
    __syncthreads();
#pragma unroll
    for (int j = 0; j < 2; ++j) {
      const int ci = (j * 4 + wv) * 64;   // wave-uniform entry base
      const int c = ci + lane;
      const int kc = c >> 7;
      const int r = c & 127;
      const int k = k0 + kc * 8;
      const u16 *aH = pAh, *aL = pAl;
      long ka = k;
      if (k >= kSplitA) { aH = pAh2; aL = pAl2; ka = k - kSplitA; }
      const long aoff = (m0 + r) * (long)lda + ka;
      gload16(aH + aoff, &lds[0][ci * 8]);
      if constexpr (NPROD >= 2) gload16(aL + aoff, &lds[2][ci * 8]);
      const long boff = (n0 + r) * (long)ldb + k;
      gload16(pBh + boff, &lds[1][ci * 8]);
      if constexpr (NPROD >= 3) gload16(pBl + boff, &lds[3][ci * 8]);
    }
    __syncthreads();

    s16x8 ah[4], al[4], bh[4], bl[4];
#pragma unroll
    for (int f = 0; f < 4; ++f) {
      const int ra = wm * 64 + f * 16 + lr;
      const int rb = wn * 64 + f * 16 + lr;
      ah[f] = *(const s16x8*)&lds[0][lk * 1024 + ra * 8];
      bh[f] = *(const s16x8*)&lds[1][lk * 1024 + rb * 8];
      if constexpr (NPROD >= 2) al[f] = *(const s16x8*)&lds[2][lk * 1024 + ra * 8];
      if constexpr (NPROD >= 3) bl[f] = *(const s16x8*)&lds[3][lk * 1024 + rb * 8];
    }
#pragma unroll
    for (int i = 0; i < 4; ++i)
#pragma unroll
      for (int j = 0; j < 4; ++j) {
        acc[i][j] = __builtin_amdgcn_mfma_f32_16x16x32_bf16(ah[i], bh[j], acc[i][j], 0, 0, 0);
        if constexpr (NPROD >= 3)
          acc[i][j] = __builtin_amdgcn_mfma_f32_16x16x32_bf16(ah[i], bl[j], acc[i][j], 0, 0, 0);
        if constexpr (NPROD >= 2)
          acc[i][j] = __builtin_amdgcn_mfma_f32_16x16x32_bf16(al[i], bh[j], acc[i][j], 0, 0, 0);
      }
  }

#pragma unroll
  for (int fm = 0; fm < 4; ++fm)
#pragma unroll
    for (int fn = 0; fn < 4; ++fn)
#pragma unroll
      for (int r = 0; r < 4; ++r) {
        const long row = m0 + wm * 64 + fm * 16 + (lane >> 4) * 4 + r;
        const long col = n0 + wn * 64 + fn * 16 + lr;
        const float v = acc[fm][fn][r];
        if constexpr (EP == 0) {
          Cf[(long)bz * sC + row * ldc + col] = v;
        } else if constexpr (EP == 1) {
          u16 h, l; split_bf(v, h, l);
          const long o = (long)bz * sC + row * ldc + col;
          Ch[o] = h; Cl[o] = l;
        }
      }
}

// ========== Template R (proven, G2): 128x128, BK=32, 4 waves, reg-staged, bf16 3-prod ==========
// A pre-split bf16 hi/lo; B split ON-THE-FLY from f32. EP: 0 = f32 C. MASK: 1 = maskN early-exit.
template<int EP, int MASK>
__global__ __launch_bounds__(256, 2) void gemmR(
    const u16* __restrict__ Ah, const u16* __restrict__ Al, int lda, long sA,
    const float* __restrict__ Bf, int ldb, long sB,
    int K, const int* __restrict__ lens,
    float* __restrict__ Cf, u16* __restrict__ Ch, u16* __restrict__ Cl,
    int ldc, long sC, int lgx, int lgxy, int nwg) {
  __shared__ __align__(16) u16 ldsA[2][4096];   // [hi/lo][ [kc(4)][row(128)][8] ]
  __shared__ __align__(16) u16 ldsB[2][4096];

  const int orig = blockIdx.x;
  const int wg = (orig & 7) * (nwg >> 3) + (orig >> 3);
  const int bx = wg & ((1 << lgx) - 1);
  const int by = (wg >> lgx) & ((1 << (lgxy - lgx)) - 1);
  const int bz = wg >> lgxy;

  const long m0 = (long)by * 128;
  const long n0 = (long)bx * 128;

  if constexpr (MASK == 1) {
    if (n0 >= lens[bz]) return;        // block-uniform, before any barrier
  }

  const u16* pAh = Ah + (long)bz * sA;
  const u16* pAl = Al + (long)bz * sA;
  const float* pBf = Bf + (long)bz * sB;

  const int t = threadIdx.x;
  const int lane = t & 63;
  const int wv = t >> 6;
  const int wm = wv >> 1;
  const int wn = wv & 1;
  const int lk = lane >> 4;
  const int lr = lane & 15;
  const int fragBase = lk * 1024;

  f32x4 acc[4][4];
#pragma unroll
  for (int i = 0; i < 4; ++i)
#pragma unroll
    for (int j = 0; j < 4; ++j) acc[i][j] = 0.0f;

  for (int k0 = 0; k0 < K; k0 += 32) {
    __syncthreads();
#pragma unroll
    for (int j = 0; j < 2; ++j) {
      const int c = j * 256 + t;
      const int kc = c >> 7, r = c & 127;
      const int k = k0 + kc * 8;
      const long aoff = (m0 + r) * (long)lda + k;
      *(u16x8*)&ldsA[0][c * 8] = *(const u16x8*)(pAh + aoff);
      *(u16x8*)&ldsA[1][c * 8] = *(const u16x8*)(pAl + aoff);
      const float* s = pBf + (n0 + r) * (long)ldb + k;
      u16x8 bh, bl;
#pragma unroll
      for (int e = 0; e < 8; ++e) { u16 hh, ll; split_bf(s[e], hh, ll); bh[e] = hh; bl[e] = ll; }
      *(u16x8*)&ldsB[0][c * 8] = bh;
      *(u16x8*)&ldsB[1][c * 8] = bl;
    }
    __syncthreads();

    s16x8 ah[4], al[4], bh[4], bl[4];
#pragma unroll
    for (int f = 0; f < 4; ++f) {
      const int ra = wm * 64 + f * 16 + lr;
      const int rb = wn * 64 + f * 16 + lr;
      ah[f] = *(const s16x8*)&ldsA[0][fragBase + ra * 8];
      al[f] = *(const s16x8*)&ldsA[1][fragBase + ra * 8];
      bh[f] = *(const s16x8*)&ldsB[0][fragBase + rb * 8];
      bl[f] = *(const s16x8*)&ldsB[1][fragBase + rb * 8];
    }
#pragma unroll
    for (int i = 0; i < 4; ++i)
#pragma unroll
      for (int j = 0; j < 4; ++j) {
        acc[i][j] = __builtin_amdgcn_mfma_f32_16x16x32_bf16(ah[i], bh[j], acc[i][j], 0, 0, 0);
        acc[i][j] = __builtin_amdgcn_mfma_f32_16x16x32_bf16(ah[i], bl[j], acc[i][j], 0, 0, 0);
        acc[i][j] = __builtin_amdgcn_mfma_f32_16x16x32_bf16(al[i], bh[j], acc[i][j], 0, 0, 0);
      }
  }

#pragma unroll
  for (int fm = 0; fm < 4; ++fm)
#pragma unroll
    for (int fn = 0; fn < 4; ++fn)
#pragma unroll
      for (int r = 0; r < 4; ++r) {
        const long row = m0 + wm * 64 + fm * 16 + (lane >> 4) * 4 + r;
        const long col = n0 + wn * 64 + fn * 16 + lr;
        const float v = acc[fm][fn][r];
        if constexpr (EP == 0) {
          Cf[(long)bz * sC + row * ldc + col] = v;
        } else {
          u16 h, l; split_bf(v, h, l);
          const long o = (long)bz * sC + row * ldc + col;
          Ch[o] = h; Cl[o] = l;
        }
      }
}

// ========== Template W: 256x128 tile, BK=64, 512 thr (8 waves: 4m x 2n), fp16 1-prod ==========
// EP: 2 = tanh + [T,B,D] transposed f32 store; 3 = fp16 C store.
// MASK: 0 none; 2 = truncate K at ceil(lens[bz]/64)*64.
template<int EP, int MASK>
__global__ __launch_bounds__(512) void gemmW(
    const u16* __restrict__ A1, const u16* __restrict__ A2, int kSplitA, int lda, long sA,
    const u16* __restrict__ B, int ldb, long sB,
    int K, const int* __restrict__ lens,
    float* __restrict__ Cf, u16* __restrict__ Ch,
    int ldc, long sC, int lgx, int lgxy, int nwg) {
  __shared__ __align__(16) u16 ldsA[16384];  // [kc(8)][row(256)][8]  32KB
  __shared__ __align__(16) u16 ldsB[8192];   // [kc(8)][row(128)][8]  16KB

  const int orig = blockIdx.x;
  const int wg = (orig & 7) * (nwg >> 3) + (orig >> 3);
  const int bx = wg & ((1 << lgx) - 1);
  const int by = (wg >> lgx) & ((1 << (lgxy - lgx)) - 1);
  const int bz = wg >> lgxy;

  const long m0 = (long)by * 256;
  const long n0 = (long)bx * 128;

  int Klim = K;
  if constexpr (MASK == 2) {
    const int kl = (lens[bz] + 63) & ~63;
    Klim = kl < K ? kl : K;
  }

  const u16* pA1 = A1 + (long)bz * sA;
  const u16* pA2 = A2 + (long)bz * sA;
  const u16* pB  = B  + (long)bz * sB;

  const int t = threadIdx.x;
  const int lane = t & 63;
  const int wv = t >> 6;        // 0..7
  const int wm = wv >> 1;       // 0..3  (M quarter, 64 rows)
  const int wn = wv & 1;        // 0..1  (N half, 64 cols)
  const int lk = lane >> 4;     // 0..3
  const int lr = lane & 15;

  f32x4 acc[4][4];
#pragma unroll
  for (int i = 0; i < 4; ++i)
#pragma unroll
    for (int j = 0; j < 4; ++j) acc[i][j] = 0.0f;

  for (int k0 = 0; k0 < Klim; k0 += 64) {
    __syncthreads();
#pragma unroll
    for (int j = 0; j < 4; ++j) {
      const int ci = (j * 8 + wv) * 64;   // 64-aligned -> kc uniform in chunk
      const int c = ci + lane;
      const int kc = c >> 8;              // 0..7
      const int r = c & 255;
      const int k = k0 + kc * 8;
      const u16* a = pA1; long ka = k;
      if (k >= kSplitA) { a = pA2; ka = k - kSplitA; }
      gload16(a + (m0 + r) * (long)lda + ka, &ldsA[ci * 8]);
    }
#pragma unroll
    for (int j = 0; j < 2; ++j) {
      const int ci = (j * 8 + wv) * 64;
      const int c = ci + lane;
      const int kc = c >> 7;              // 0..7
      const int r = c & 127;
      const int k = k0 + kc * 8;
      gload16(pB + (n0 + r) * (long)ldb + k, &ldsB[ci * 8]);
    }
    __syncthreads();

#pragma unroll
    for (int ks = 0; ks < 2; ++ks) {
      const int kc = ks * 4 + lk;         // 0..7
      f16x8 a[4], b[4];
#pragma unroll
      for (int f = 0; f < 4; ++f) {
        const int ra = wm * 64 + f * 16 + lr;
        const int rb = wn * 64 + f * 16 + lr;
        a[f] = *(const f16x8*)&ldsA[(kc * 256 + ra) * 8];
        b[f] = *(const f16x8*)&ldsB[(kc * 128 + rb) * 8];
      }
#pragma unroll
      for (int i = 0; i < 4; ++i)
#pragma unroll
        for (int j = 0; j < 4; ++j)
          acc[i][j] = __builtin_amdgcn_mfma_f32_16x16x32_f16(a[i], b[j], acc[i][j], 0, 0, 0);
    }
  }

#pragma unroll
  for (int fm = 0; fm < 4; ++fm)
#pragma unroll
    for (int fn = 0; fn < 4; ++fn)
#pragma unroll
      for (int r = 0; r < 4; ++r) {
        const long row = m0 + wm * 64 + fm * 16 + (lane >> 4) * 4 + r;
        const long col = n0 + wn * 64 + fn * 16 + lr;
        const float v = acc[fm][fn][r];
        if constexpr (EP == 2) {
          const long bb = row >> 10;       // batch (T=1024)
          const long tt = row & 1023;      // t
          Cf[(tt * 16 + bb) * (long)ldc + col] = tanhf(v);
        } else {
          Ch[(long)bz * sC + row * ldc + col] = f2h(v);
        }
      }
}

extern "C" void kernel_launch(void* const* d_in, const int* in_sizes, int n_in,
                              void* d_out, int out_size, void* d_ws, size_t ws_size,
                              hipStream_t stream) {
  (void)in_sizes; (void)n_in; (void)out_size; (void)ws_size;
  const float* src = (const float*)d_in[0];   // [16,1024,1024]
  const float* mb  = (const float*)d_in[1];   // [16,2048,1024]
  const int*   lens= (const int*)d_in[2];     // [16]
  const float* Wi  = (const float*)d_in[3];   // [1024,1024]
  const float* Wo  = (const float*)d_in[4];   // [1024,2048]
  float* out = (float*)d_out;                 // attn [T,B,D] f32, then P [T,B,S] f32

  // workspace (292 MiB used)
  char* p = (char*)d_ws;
  u16* srcU_hi = (u16*)p;                         // 32 MiB bf16 (G1 A; dead after G1 -> mbT)
  u16* srcU_lo = (u16*)(p + (32L << 20));         // 32 MiB bf16 (G1 A; dead after G1 -> mbT)
  u16* htc_hi  = (u16*)(p + (64L << 20));         // 32 MiB h_t hi (G1 out, G2 A) -> c fp16 (G3 out)
  u16* htc_lo  = (u16*)(p + (96L << 20));         // 32 MiB h_t lo (dead after G2)
  u16* srcF16  = (u16*)(p + (128L << 20));        // 32 MiB fp16 (G4)
  u16* Wo_f16  = (u16*)(p + (160L << 20));        // 4 MiB fp16 (G4)
  float* alignBuf = (float*)(p + (164L << 20));   // 128 MiB [16][1024][2048] f32
  u16* Wi_hi = (u16*)alignBuf;                    // borrow head of alignBuf (G1 reads; G2 overwrites after)
  u16* Wi_lo = Wi_hi + 1048576;
  u16* mbT   = srcU_hi;                           // [b][D][S] fp16, 64 MiB = srcU hi+lo exactly

  dim3 blk(256);
  split_copy_k<<<dim3(16384), blk, 0, stream>>>(src, srcU_hi, srcU_lo, 4194304L);
  split_copy_k<<<dim3(1024),  blk, 0, stream>>>(Wi,  Wi_hi,  Wi_lo,  262144L);
  copy_f16_k<<<dim3(16384), blk, 0, stream>>>(src, srcF16, 4194304L);
  copy_f16_k<<<dim3(2048),  blk, 0, stream>>>(Wo,  Wo_f16, 524288L);

  // G1: h_t = src @ Wi^T  (M=16384,N=1024,K=1024), gemm128 bf16 3-prod, split store
  gemm128<3, 1, 0><<<dim3(1024), blk, 0, stream>>>(
      srcU_hi, srcU_lo, srcU_hi, srcU_lo, 1 << 30, 1024, 0L,
      Wi_hi, Wi_lo, 1024, 0L,
      1024, lens,
      nullptr, htc_hi, htc_lo, 1024, 0L,
      3, 10, 1024);

  // G2: align[b] = h_t[b] @ mb[b]^T  (M=1024,N=2048,K=1024)x16, gemmR 3-prod (B=mb f32), maskN
  gemmR<0, 1><<<dim3(2048), blk, 0, stream>>>(
      htc_hi, htc_lo, 1024, 1048576L,
      mb, 1024, 2097152L,
      1024, lens,
      alignBuf, nullptr, nullptr, 2048, 2097152L,
      4, 7, 2048);

  // masked softmax; P f32 -> d_out[1], P fp16 packed in place over alignBuf rows
  softmax_k<<<dim3(16384), blk, 0, stream>>>(alignBuf, lens, out + 16777216L);

  // mbT (fp16 transpose of f32 mb) into srcU region (dead after G1)
  transpose_f16_k<<<dim3(32, 16, 16), blk, 0, stream>>>(mb, mbT);

  // G3: c[b] = P[b] @ mbT[b]^T  (M=1024,N=1024,K=2048)x16, fp16 1-prod, fp16 store (over htc_hi), maskK
  gemmW<3, 2><<<dim3(512), dim3(512), 0, stream>>>(
      (const u16*)alignBuf, (const u16*)alignBuf, 1 << 30, 4096, 4194304L,
      mbT, 2048, 2097152L,
      2048, lens,
      nullptr, htc_hi, 1024, 1048576L,
      3, 5, 512);

  // G4: attn = tanh([c,src] @ Wo^T)  (M=16384,N=1024,K=2048), fp16 1-prod, tanh+transpose store
  gemmW<2, 0><<<dim3(512), dim3(512), 0, stream>>>(
      htc_hi, srcF16, 1024, 1024, 0L,
      Wo_f16, 2048, 0L,
      2048, lens,
      out, nullptr, 1024, 0L,
      3, 9, 512);
}

// Round 18
// 794.980 us; speedup vs baseline: 1.0885x; 1.0056x over previous
//
#include <hip/hip_runtime.h>

typedef __attribute__((ext_vector_type(8))) short s16x8;
typedef __attribute__((ext_vector_type(8))) unsigned short u16x8;
typedef __attribute__((ext_vector_type(8))) _Float16 f16x8;
typedef __attribute__((ext_vector_type(4))) float f32x4;
typedef __attribute__((ext_vector_type(4))) unsigned short u16x4;
typedef unsigned short u16;

// ---------- bf16 helpers (RNE) ----------
__device__ __forceinline__ u16 f2bf(float x) {
  unsigned u = __builtin_bit_cast(unsigned, x);
  u = u + 0x7fffu + ((u >> 16) & 1u);
  return (u16)(u >> 16);
}
__device__ __forceinline__ float bf2f(u16 h) {
  return __builtin_bit_cast(float, (unsigned)h << 16);
}
__device__ __forceinline__ void split_bf(float x, u16 &h, u16 &l) {
  h = f2bf(x); l = f2bf(x - bf2f(h));
}
__device__ __forceinline__ u16 f2h(float x) {
  return __builtin_bit_cast(u16, (_Float16)x);
}

// ---------- async global -> LDS, 16B per lane ----------
typedef __attribute__((address_space(1))) const unsigned int as1c_u32;
typedef __attribute__((address_space(3))) unsigned int as3_u32;
__device__ __forceinline__ void gload16(const void* g, void* l) {
  __builtin_amdgcn_global_load_lds((as1c_u32*)g, (as3_u32*)l, 16, 0, 0);
}

// ---------- fused src prep: f32 -> bf16 hi/lo + fp16, single read ----------
__global__ __launch_bounds__(256) void prep_src_k(
    const float* __restrict__ in, u16* __restrict__ oh, u16* __restrict__ ol,
    u16* __restrict__ of, long n4) {
  const long i = (long)blockIdx.x * 256 + threadIdx.x;
  if (i >= n4) return;
  const f32x4 v = *(const f32x4*)(in + i * 4);
  u16x4 h, l, f;
#pragma unroll
  for (int e = 0; e < 4; ++e) {
    u16 hh, ll; split_bf(v[e], hh, ll);
    h[e] = hh; l[e] = ll; f[e] = f2h(v[e]);
  }
  *(u16x4*)(oh + i * 4) = h;
  *(u16x4*)(ol + i * 4) = l;
  *(u16x4*)(of + i * 4) = f;
}

// ---------- vectorized split: f32 -> hi/lo bf16 ----------
__global__ __launch_bounds__(256) void split_copy_k(
    const float* __restrict__ in, u16* __restrict__ oh, u16* __restrict__ ol, long n4) {
  const long i = (long)blockIdx.x * 256 + threadIdx.x;
  if (i >= n4) return;
  const f32x4 v = *(const f32x4*)(in + i * 4);
  u16x4 h, l;
#pragma unroll
  for (int e = 0; e < 4; ++e) { u16 hh, ll; split_bf(v[e], hh, ll); h[e] = hh; l[e] = ll; }
  *(u16x4*)(oh + i * 4) = h;
  *(u16x4*)(ol + i * 4) = l;
}

// ---------- f32 -> fp16 copy ----------
__global__ __launch_bounds__(256) void copy_f16_k(
    const float* __restrict__ in, u16* __restrict__ oh, long n4) {
  const long i = (long)blockIdx.x * 256 + threadIdx.x;
  if (i >= n4) return;
  const f32x4 v = *(const f32x4*)(in + i * 4);
  u16x4 h;
#pragma unroll
  for (int e = 0; e < 4; ++e) h[e] = f2h(v[e]);
  *(u16x4*)(oh + i * 4) = h;
}

// ---------- transpose to fp16: mb [b][S=2048][D=1024] f32 -> mbT [b][D][S] fp16 ----------
__global__ __launch_bounds__(256) void transpose_f16_k(
    const float* __restrict__ in, u16* __restrict__ oh) {
  __shared__ float tile[64][65];
  const int b = blockIdx.z;
  const int s0 = blockIdx.x * 64, d0 = blockIdx.y * 64;
  const float* pin = in + (long)b * 2048 * 1024;
  const int t = threadIdx.x;
#pragma unroll
  for (int i = 0; i < 16; ++i) {
    const int idx = i * 256 + t;
    const int r = idx >> 6, c = idx & 63;
    tile[r][c] = pin[(long)(s0 + r) * 1024 + d0 + c];
  }
  __syncthreads();
  u16* poh = oh + (long)b * 1024 * 2048;
#pragma unroll
  for (int i = 0; i < 16; ++i) {
    const int idx = i * 256 + t;
    const int r = idx >> 6, c = idx & 63;   // r: d, c: s
    poh[(long)(d0 + r) * 2048 + s0 + c] = f2h(tile[c][r]);
  }
}

// ---------- masked softmax over S=2048; P f32 -> out [T,B,S]; P fp16 packed in place ----------
__global__ __launch_bounds__(256) void softmax_k(
    float* __restrict__ alignBuf, const int* __restrict__ lens, float* __restrict__ outP) {
  const int row = blockIdx.x;          // b*1024 + t
  const int b = row >> 10;
  const int tt = row & 1023;
  const int len = lens[b];
  float* arow = alignBuf + (long)row * 2048;
  const int t = threadIdx.x;
  const int lane = t & 63, wv = t >> 6;
  float v[8];
  float mx = -3.0e38f;
#pragma unroll
  for (int j = 0; j < 8; ++j) {
    const int s = j * 256 + t;
    const float x = (s < len) ? arow[s] : -1.0e9f;   // skip masked loads
    v[j] = x;
    mx = fmaxf(mx, x);
  }
#pragma unroll
  for (int off = 32; off; off >>= 1) mx = fmaxf(mx, __shfl_xor(mx, off));
  __shared__ float redm[4], reds[4];
  if (lane == 0) redm[wv] = mx;
  __syncthreads();
  mx = fmaxf(fmaxf(redm[0], redm[1]), fmaxf(redm[2], redm[3]));
  float e[8]; float sum = 0.f;
#pragma unroll
  for (int j = 0; j < 8; ++j) { e[j] = __expf(v[j] - mx); sum += e[j]; }
#pragma unroll
  for (int off = 32; off; off >>= 1) sum += __shfl_xor(sum, off);
  if (lane == 0) reds[wv] = sum;
  __syncthreads();   // fences all reads of arow before in-place overwrite below
  sum = reds[0] + reds[1] + reds[2] + reds[3];
  const float inv = 1.0f / sum;
  u16* ph = (u16*)arow;          // [0,2048): P fp16 (first 4KB of the 8KB row)
  float* orow = outP + ((long)tt * 16 + b) * 2048;
#pragma unroll
  for (int j = 0; j < 8; ++j) {
    const int s = j * 256 + t;
    const float pv = e[j] * inv;
    orow[s] = pv;
    ph[s] = f2h(pv);             // exact 0 beyond len -> maskK in G3 exact
  }
}

// ========== Template A (proven, G1): 128x128, BK=32, single-buf, glds, bf16 3-prod ==========
template<int NPROD, int EP, int MASK>
__global__ __launch_bounds__(256) void gemm128(
    const u16* __restrict__ Ah, const u16* __restrict__ Al,
    const u16* __restrict__ Ah2, const u16* __restrict__ Al2,
    int kSplitA, int lda, long sA,
    const u16* __restrict__ Bh, const u16* __restrict__ Bl, int ldb, long sB,
    int K, const int* __restrict__ lens,
    float* __restrict__ Cf, u16* __restrict__ Ch, u16* __restrict__ Cl,
    int ldc, long sC, int lgx, int lgxy, int nwg) {
  constexpr int NT = (NPROD >= 3) ? 4 : (NPROD == 2 ? 3 : 2);
  __shared__ __align__(16) u16 lds[NT][4096];   // [kc(4)][row(128)][8]

  const int orig = blockIdx.x;
  const int wg = (orig & 7) * (nwg >> 3) + (orig >> 3);
  const int bx = wg & ((1 << lgx) - 1);
  const int by = (wg >> lgx) & ((1 << (lgxy - lgx)) - 1);
  const int bz = wg >> lgxy;

  const long m0 = (long)by * 128;
  const long n0 = (long)bx * 128;

  if constexpr (MASK == 1) {
    if (n0 >= lens[bz]) return;        // block-uniform, before any barrier
  }

  const u16* pAh  = Ah  + (long)bz * sA;
  const u16* pAl  = Al  + (long)bz * sA;
  const u16* pAh2 = Ah2 + (long)bz * sA;
  const u16* pAl2 = Al2 + (long)bz * sA;
  const u16* pBh  = Bh  + (long)bz * sB;
  const u16* pBl  = Bl  + (long)bz * sB;

  const int t = threadIdx.x;
  const int lane = t & 63;
  const int wv = t >> 6;
  const int wm = wv >> 1;
  const int wn = wv & 1;
  const int lk = lane >> 4;
  const int lr = lane & 15;

  f32x4 acc[4][4];
#pragma unroll
  for (int i = 0; i < 4; ++i)
#pragma unroll
    for (int j = 0; j < 4; ++j) acc[i][j] = 0.0f;

  for (int k0 = 0; k0 < K; k0 += 32) {
    __syncthreads();
#pragma unroll
    for (int j = 0; j < 2; ++j) {
      const int ci = (j * 4 + wv) * 64;   // wave-uniform entry base
      const int c = ci + lane;
      const int kc = c >> 7;
      const int r = c & 127;
      const int k = k0 + kc * 8;
      const u16 *aH = pAh, *aL = pAl;
      long ka = k;
      if (k >= kSplitA) { aH = pAh2; aL = pAl2; ka = k - kSplitA; }
      const long aoff = (m0 + r) * (long)lda + ka;
      gload16(aH + aoff, &lds[0][ci * 8]);
      if constexpr (NPROD >= 2) gload16(aL + aoff, &lds[2][ci * 8]);
      const long boff = (n0 + r) * (long)ldb + k;
      gload16(pBh + boff, &lds[1][ci * 8]);
      if constexpr (NPROD >= 3) gload16(pBl + boff, &lds[3][ci * 8]);
    }
    __syncthreads();

    s16x8 ah[4], al[4], bh[4], bl[4];
#pragma unroll
    for (int f = 0; f < 4; ++f) {
      const int ra = wm * 64 + f * 16 + lr;
      const int rb = wn * 64 + f * 16 + lr;
      ah[f] = *(const s16x8*)&lds[0][lk * 1024 + ra * 8];
      bh[f] = *(const s16x8*)&lds[1][lk * 1024 + rb * 8];
      if constexpr (NPROD >= 2) al[f] = *(const s16x8*)&lds[2][lk * 1024 + ra * 8];
      if constexpr (NPROD >= 3) bl[f] = *(const s16x8*)&lds[3][lk * 1024 + rb * 8];
    }
#pragma unroll
    for (int i = 0; i < 4; ++i)
#pragma unroll
      for (int j = 0; j < 4; ++j) {
        acc[i][j] = __builtin_amdgcn_mfma_f32_16x16x32_bf16(ah[i], bh[j], acc[i][j], 0, 0, 0);
        if constexpr (NPROD >= 3)
          acc[i][j] = __builtin_amdgcn_mfma_f32_16x16x32_bf16(ah[i], bl[j], acc[i][j], 0, 0, 0);
        if constexpr (NPROD >= 2)
          acc[i][j] = __builtin_amdgcn_mfma_f32_16x16x32_bf16(al[i], bh[j], acc[i][j], 0, 0, 0);
      }
  }

#pragma unroll
  for (int fm = 0; fm < 4; ++fm)
#pragma unroll
    for (int fn = 0; fn < 4; ++fn)
#pragma unroll
      for (int r = 0; r < 4; ++r) {
        const long row = m0 + wm * 64 + fm * 16 + (lane >> 4) * 4 + r;
        const long col = n0 + wn * 64 + fn * 16 + lr;
        const float v = acc[fm][fn][r];
        if constexpr (EP == 0) {
          Cf[(long)bz * sC + row * ldc + col] = v;
        } else if constexpr (EP == 1) {
          u16 h, l; split_bf(v, h, l);
          const long o = (long)bz * sC + row * ldc + col;
          Ch[o] = h; Cl[o] = l;
        }
      }
}

// ========== Template R (proven, G2): 128x128, BK=32, 4 waves, reg-staged, bf16 3-prod ==========
template<int EP, int MASK>
__global__ __launch_bounds__(256, 2) void gemmR(
    const u16* __restrict__ Ah, const u16* __restrict__ Al, int lda, long sA,
    const float* __restrict__ Bf, int ldb, long sB,
    int K, const int* __restrict__ lens,
    float* __restrict__ Cf, u16* __restrict__ Ch, u16* __restrict__ Cl,
    int ldc, long sC, int lgx, int lgxy, int nwg) {
  __shared__ __align__(16) u16 ldsA[2][4096];   // [hi/lo][ [kc(4)][row(128)][8] ]
  __shared__ __align__(16) u16 ldsB[2][4096];

  const int orig = blockIdx.x;
  const int wg = (orig & 7) * (nwg >> 3) + (orig >> 3);
  const int bx = wg & ((1 << lgx) - 1);
  const int by = (wg >> lgx) & ((1 << (lgxy - lgx)) - 1);
  const int bz = wg >> lgxy;

  const long m0 = (long)by * 128;
  const long n0 = (long)bx * 128;

  if constexpr (MASK == 1) {
    if (n0 >= lens[bz]) return;        // block-uniform, before any barrier
  }

  const u16* pAh = Ah + (long)bz * sA;
  const u16* pAl = Al + (long)bz * sA;
  const float* pBf = Bf + (long)bz * sB;

  const int t = threadIdx.x;
  const int lane = t & 63;
  const int wv = t >> 6;
  const int wm = wv >> 1;
  const int wn = wv & 1;
  const int lk = lane >> 4;
  const int lr = lane & 15;
  const int fragBase = lk * 1024;

  f32x4 acc[4][4];
#pragma unroll
  for (int i = 0; i < 4; ++i)
#pragma unroll
    for (int j = 0; j < 4; ++j) acc[i][j] = 0.0f;

  for (int k0 = 0; k0 < K; k0 += 32) {
    __syncthreads();
#pragma unroll
    for (int j = 0; j < 2; ++j) {
      const int c = j * 256 + t;
      const int kc = c >> 7, r = c & 127;
      const int k = k0 + kc * 8;
      const long aoff = (m0 + r) * (long)lda + k;
      *(u16x8*)&ldsA[0][c * 8] = *(const u16x8*)(pAh + aoff);
      *(u16x8*)&ldsA[1][c * 8] = *(const u16x8*)(pAl + aoff);
      const float* s = pBf + (n0 + r) * (long)ldb + k;
      u16x8 bh, bl;
#pragma unroll
      for (int e = 0; e < 8; ++e) { u16 hh, ll; split_bf(s[e], hh, ll); bh[e] = hh; bl[e] = ll; }
      *(u16x8*)&ldsB[0][c * 8] = bh;
      *(u16x8*)&ldsB[1][c * 8] = bl;
    }
    __syncthreads();

    s16x8 ah[4], al[4], bh[4], bl[4];
#pragma unroll
    for (int f = 0; f < 4; ++f) {
      const int ra = wm * 64 + f * 16 + lr;
      const int rb = wn * 64 + f * 16 + lr;
      ah[f] = *(const s16x8*)&ldsA[0][fragBase + ra * 8];
      al[f] = *(const s16x8*)&ldsA[1][fragBase + ra * 8];
      bh[f] = *(const s16x8*)&ldsB[0][fragBase + rb * 8];
      bl[f] = *(const s16x8*)&ldsB[1][fragBase + rb * 8];
    }
#pragma unroll
    for (int i = 0; i < 4; ++i)
#pragma unroll
      for (int j = 0; j < 4; ++j) {
        acc[i][j] = __builtin_amdgcn_mfma_f32_16x16x32_bf16(ah[i], bh[j], acc[i][j], 0, 0, 0);
        acc[i][j] = __builtin_amdgcn_mfma_f32_16x16x32_bf16(ah[i], bl[j], acc[i][j], 0, 0, 0);
        acc[i][j] = __builtin_amdgcn_mfma_f32_16x16x32_bf16(al[i], bh[j], acc[i][j], 0, 0, 0);
      }
  }

#pragma unroll
  for (int fm = 0; fm < 4; ++fm)
#pragma unroll
    for (int fn = 0; fn < 4; ++fn)
#pragma unroll
      for (int r = 0; r < 4; ++r) {
        const long row = m0 + wm * 64 + fm * 16 + (lane >> 4) * 4 + r;
        const long col = n0 + wn * 64 + fn * 16 + lr;
        const float v = acc[fm][fn][r];
        if constexpr (EP == 0) {
          Cf[(long)bz * sC + row * ldc + col] = v;
        } else {
          u16 h, l; split_bf(v, h, l);
          const long o = (long)bz * sC + row * ldc + col;
          Ch[o] = h; Cl[o] = l;
        }
      }
}

// ========== Template W: 256x128 tile, BK=64, 512 thr (8 waves: 4m x 2n), fp16 1-prod ==========
template<int EP, int MASK>
__global__ __launch_bounds__(512) void gemmW(
    const u16* __restrict__ A1, const u16* __restrict__ A2, int kSplitA, int lda, long sA,
    const u16* __restrict__ B, int ldb, long sB,
    int K, const int* __restrict__ lens,
    float* __restrict__ Cf, u16* __restrict__ Ch,
    int ldc, long sC, int lgx, int lgxy, int nwg) {
  __shared__ __align__(16) u16 ldsA[16384];  // [kc(8)][row(256)][8]  32KB
  __shared__ __align__(16) u16 ldsB[8192];   // [kc(8)][row(128)][8]  16KB

  const int orig = blockIdx.x;
  const int wg = (orig & 7) * (nwg >> 3) + (orig >> 3);
  const int bx = wg & ((1 << lgx) - 1);
  const int by = (wg >> lgx) & ((1 << (lgxy - lgx)) - 1);
  const int bz = wg >> lgxy;

  const long m0 = (long)by * 256;
  const long n0 = (long)bx * 128;

  int Klim = K;
  if constexpr (MASK == 2) {
    const int kl = (lens[bz] + 63) & ~63;
    Klim = kl < K ? kl : K;
  }

  const u16* pA1 = A1 + (long)bz * sA;
  const u16* pA2 = A2 + (long)bz * sA;
  const u16* pB  = B  + (long)bz * sB;

  const int t = threadIdx.x;
  const int lane = t & 63;
  const int wv = t >> 6;        // 0..7
  const int wm = wv >> 1;       // 0..3  (M quarter, 64 rows)
  const int wn = wv & 1;        // 0..1  (N half, 64 cols)
  const int lk = lane >> 4;     // 0..3
  const int lr = lane & 15;

  f32x4 acc[4][4];
#pragma unroll
  for (int i = 0; i < 4; ++i)
#pragma unroll
    for (int j = 0; j < 4; ++j) acc[i][j] = 0.0f;

  for (int k0 = 0; k0 < Klim; k0 += 64) {
    __syncthreads();
#pragma unroll
    for (int j = 0; j < 4; ++j) {
      const int ci = (j * 8 + wv) * 64;   // 64-aligned -> kc uniform in chunk
      const int c = ci + lane;
      const int kc = c >> 8;              // 0..7
      const int r = c & 255;
      const int k = k0 + kc * 8;
      const u16* a = pA1; long ka = k;
      if (k >= kSplitA) { a = pA2; ka = k - kSplitA; }
      gload16(a + (m0 + r) * (long)lda + ka, &ldsA[ci * 8]);
    }
#pragma unroll
    for (int j = 0; j < 2; ++j) {
      const int ci = (j * 8 + wv) * 64;
      const int c = ci + lane;
      const int kc = c >> 7;              // 0..7
      const int r = c & 127;
      const int k = k0 + kc * 8;
      gload16(pB + (n0 + r) * (long)ldb + k, &ldsB[ci * 8]);
    }
    __syncthreads();

#pragma unroll
    for (int ks = 0; ks < 2; ++ks) {
      const int kc = ks * 4 + lk;         // 0..7
      f16x8 a[4], b[4];
#pragma unroll
      for (int f = 0; f < 4; ++f) {
        const int ra = wm * 64 + f * 16 + lr;
        const int rb = wn * 64 + f * 16 + lr;
        a[f] = *(const f16x8*)&ldsA[(kc * 256 + ra) * 8];
        b[f] = *(const f16x8*)&ldsB[(kc * 128 + rb) * 8];
      }
#pragma unroll
      for (int i = 0; i < 4; ++i)
#pragma unroll
        for (int j = 0; j < 4; ++j)
          acc[i][j] = __builtin_amdgcn_mfma_f32_16x16x32_f16(a[i], b[j], acc[i][j], 0, 0, 0);
    }
  }

#pragma unroll
  for (int fm = 0; fm < 4; ++fm)
#pragma unroll
    for (int fn = 0; fn < 4; ++fn)
#pragma unroll
      for (int r = 0; r < 4; ++r) {
        const long row = m0 + wm * 64 + fm * 16 + (lane >> 4) * 4 + r;
        const long col = n0 + wn * 64 + fn * 16 + lr;
        const float v = acc[fm][fn][r];
        if constexpr (EP == 2) {
          const long bb = row >> 10;       // batch (T=1024)
          const long tt = row & 1023;      // t
          Cf[(tt * 16 + bb) * (long)ldc + col] = tanhf(v);
        } else {
          Ch[(long)bz * sC + row * ldc + col] = f2h(v);
        }
      }
}

extern "C" void kernel_launch(void* const* d_in, const int* in_sizes, int n_in,
                              void* d_out, int out_size, void* d_ws, size_t ws_size,
                              hipStream_t stream) {
  (void)in_sizes; (void)n_in; (void)out_size; (void)ws_size;
  const float* src = (const float*)d_in[0];   // [16,1024,1024]
  const float* mb  = (const float*)d_in[1];   // [16,2048,1024]
  const int*   lens= (const int*)d_in[2];     // [16]
  const float* Wi  = (const float*)d_in[3];   // [1024,1024]
  const float* Wo  = (const float*)d_in[4];   // [1024,2048]
  float* out = (float*)d_out;                 // attn [T,B,D] f32, then P [T,B,S] f32

  // workspace (292 MiB used) — round-17 proven layout
  char* p = (char*)d_ws;
  u16* srcU_hi = (u16*)p;                         // 32 MiB bf16 (G1 A; dead after G1 -> mbT)
  u16* srcU_lo = (u16*)(p + (32L << 20));         // 32 MiB bf16 (G1 A; dead after G1 -> mbT)
  u16* htc_hi  = (u16*)(p + (64L << 20));         // 32 MiB h_t hi (G1 out, G2 A) -> c fp16 (G3 out)
  u16* htc_lo  = (u16*)(p + (96L << 20));         // 32 MiB h_t lo (dead after G2)
  u16* srcF16  = (u16*)(p + (128L << 20));        // 32 MiB fp16 (G4)
  u16* Wo_f16  = (u16*)(p + (160L << 20));        // 4 MiB fp16 (G4)
  float* alignBuf = (float*)(p + (164L << 20));   // 128 MiB [16][1024][2048] f32
  u16* Wi_hi = (u16*)alignBuf;                    // borrow head of alignBuf (G1 reads; G2 overwrites after)
  u16* Wi_lo = Wi_hi + 1048576;
  u16* mbT   = srcU_hi;                           // [b][D][S] fp16, 64 MiB = srcU hi+lo exactly

  dim3 blk(256);
  // fused src prep: one read of src -> bf16 hi/lo + fp16 (saves 268 MB vs separate passes)
  prep_src_k<<<dim3(16384), blk, 0, stream>>>(src, srcU_hi, srcU_lo, srcF16, 4194304L);
  split_copy_k<<<dim3(1024),  blk, 0, stream>>>(Wi,  Wi_hi,  Wi_lo,  262144L);
  copy_f16_k<<<dim3(2048),  blk, 0, stream>>>(Wo,  Wo_f16, 524288L);

  // G1: h_t = src @ Wi^T  (M=16384,N=1024,K=1024), gemm128 bf16 3-prod, split store
  gemm128<3, 1, 0><<<dim3(1024), blk, 0, stream>>>(
      srcU_hi, srcU_lo, srcU_hi, srcU_lo, 1 << 30, 1024, 0L,
      Wi_hi, Wi_lo, 1024, 0L,
      1024, lens,
      nullptr, htc_hi, htc_lo, 1024, 0L,
      3, 10, 1024);

  // G2: align[b] = h_t[b] @ mb[b]^T  (M=1024,N=2048,K=1024)x16, gemmR 3-prod (B=mb f32), maskN
  gemmR<0, 1><<<dim3(2048), blk, 0, stream>>>(
      htc_hi, htc_lo, 1024, 1048576L,
      mb, 1024, 2097152L,
      1024, lens,
      alignBuf, nullptr, nullptr, 2048, 2097152L,
      4, 7, 2048);

  // masked softmax; P f32 -> d_out[1], P fp16 packed in place over alignBuf rows
  softmax_k<<<dim3(16384), blk, 0, stream>>>(alignBuf, lens, out + 16777216L);

  // mbT (fp16 transpose of f32 mb) into srcU region (dead after G1)
  transpose_f16_k<<<dim3(32, 16, 16), blk, 0, stream>>>(mb, mbT);

  // G3: c[b] = P[b] @ mbT[b]^T  (M=1024,N=1024,K=2048)x16, fp16 1-prod, fp16 store (over htc_hi), maskK
  gemmW<3, 2><<<dim3(512), dim3(512), 0, stream>>>(
      (const u16*)alignBuf, (const u16*)alignBuf, 1 << 30, 4096, 4194304L,
      mbT, 2048, 2097152L,
      2048, lens,
      nullptr, htc_hi, 1024, 1048576L,
      3, 5, 512);

  // G4: attn = tanh([c,src] @ Wo^T)  (M=16384,N=1024,K=2048), fp16 1-prod, tanh+transpose store
  gemmW<2, 0><<<dim3(512), dim3(512), 0, stream>>>(
      htc_hi, srcF16, 1024, 1024, 0L,
      Wo_f16, 2048, 0L,
      2048, lens,
      out, nullptr, 1024, 0L,
      3, 9, 512);
}